// Round 1
// baseline (1145.748 us; speedup 1.0000x reference)
//
#include <hip/hip_runtime.h>

// GMSA f32 baseline: conv_in+BN+window-scatter | 3x flash-attention | gather+conv_out
// d_ws layout: 6 buffers of 2^24 floats: q0 v0 q1 v1 q2 v2 (403 MB total).
// Attention writes outputs IN-PLACE over its V buffer (block-local region bijection).

__global__ __launch_bounds__(256) void k_conv_in(
    const float* __restrict__ x, const float* __restrict__ w_in,
    const float* __restrict__ b_in, const float* __restrict__ gma,
    const float* __restrict__ bta, const float* __restrict__ mu,
    const float* __restrict__ var,
    float* __restrict__ q0, float* __restrict__ v0,
    float* __restrict__ q1, float* __restrict__ v1,
    float* __restrict__ q2, float* __restrict__ v2)
{
    __shared__ float xs[96*64];     // [c][px]
    __shared__ float wl[192*49];    // [o][c-half], padded stride 49
    __shared__ float invs[192];
    __shared__ float bias[192];
    const int t    = threadIdx.x;
    const int lane = t & 63;
    const int wv   = t >> 6;
    const int pxb  = (t & 15) * 4;  // 4 pixels per thread
    const int og   = t >> 4;        // 16 groups x 12 outputs

    if (t < 192) {
        float iv = gma[t] * rsqrtf(var[t] + 1e-5f);
        invs[t] = iv;
        bias[t] = b_in[t]*iv + bta[t] - mu[t]*iv;
    }

    const int pixbase = blockIdx.x * 64;
    const int b   = pixbase >> 16;
    const int rem = pixbase & 65535;
    const int hh  = rem >> 8;
    const int ww0 = rem & 255;

    {   // stage x tile (64 px, 96 ch), coalesced
        const float* xb = x + (size_t)b*96*65536 + rem;
        #pragma unroll
        for (int k = 0; k < 24; ++k) {
            int c = k*4 + wv;
            xs[c*64 + lane] = xb[(size_t)c*65536 + lane];
        }
    }

    // window row offsets (roll folded in) per scale i, per pixel p
    int ro[3][4];
    #pragma unroll
    for (int i = 0; i < 3; ++i) {
        const int lg = 2 + i;
        const int ws = 1 << lg;
        const int sft = ws >> 1;
        const int nblk = 256 >> lg;
        int h  = (hh - sft) & 255;
        int hb = h >> lg, hr = h & (ws-1);
        int nbrow = (b*nblk + hb)*nblk;
        #pragma unroll
        for (int p = 0; p < 4; ++p) {
            int w = (ww0 + pxb + p - sft) & 255;
            ro[i][p] = (nbrow + (w >> lg))*(ws*ws) + hr*ws + (w & (ws-1));
        }
    }

    float acc[4][12];
    #pragma unroll
    for (int p = 0; p < 4; ++p)
        #pragma unroll
        for (int j = 0; j < 12; ++j) acc[p][j] = 0.f;

    for (int cp = 0; cp < 2; ++cp) {        // K split in halves of 48
        __syncthreads();
        for (int k = 0; k < 36; ++k) {      // load raw weights [192][48]
            int idx = k*256 + t;
            int o = idx / 48, ch = idx - o*48;
            wl[o*49 + ch] = w_in[o*96 + cp*48 + ch];
        }
        __syncthreads();
        const int cb = cp*48;
        for (int c = 0; c < 48; ++c) {
            float4 xa = *reinterpret_cast<const float4*>(&xs[(cb + c)*64 + pxb]);
            #pragma unroll
            for (int j = 0; j < 12; ++j) {
                float wgt = wl[(og*12 + j)*49 + c];
                acc[0][j] = fmaf(wgt, xa.x, acc[0][j]);
                acc[1][j] = fmaf(wgt, xa.y, acc[1][j]);
                acc[2][j] = fmaf(wgt, xa.z, acc[2][j]);
                acc[3][j] = fmaf(wgt, xa.w, acc[3][j]);
            }
        }
    }

    // BN scale/bias at the end (linear fold), scatter to windowed layout
    #pragma unroll
    for (int j4 = 0; j4 < 12; j4 += 4) {
        const int o   = og*12 + j4;          // multiple of 4; 4-run never crosses tensor boundary
        const int sc  = o >> 6;
        const int oc  = o & 63;
        const int c32 = oc & 31;
        const bool isv = (oc & 32) != 0;
        float* tb = (sc == 0) ? (isv ? v0 : q0)
                  : (sc == 1) ? (isv ? v1 : q1)
                              : (isv ? v2 : q2);
        #pragma unroll
        for (int p = 0; p < 4; ++p) {
            int roff = (sc == 0) ? ro[0][p] : (sc == 1) ? ro[1][p] : ro[2][p];
            float4 vv;
            vv.x = fmaf(acc[p][j4+0], invs[o+0], bias[o+0]);
            vv.y = fmaf(acc[p][j4+1], invs[o+1], bias[o+1]);
            vv.z = fmaf(acc[p][j4+2], invs[o+2], bias[o+2]);
            vv.w = fmaf(acc[p][j4+3], invs[o+3], bias[o+3]);
            *reinterpret_cast<float4*>(tb + (size_t)roff*32 + c32) = vv;
        }
    }
}

// GROUP 0: nb=32768,S=16  Q=q0 K=q1 V=v2
// GROUP 1: nb=8192, S=64  Q=q1 K=q2 V=v0
// GROUP 2: nb=2048, S=256 Q=q2 K=q0 V=v1
template<int GROUP>
__global__ __launch_bounds__(256) void k_attn(
    const float* __restrict__ Q, const float* __restrict__ Ks,
    const float* Vs, float* O)   // Vs and O may alias (in-place, block-local)
{
    constexpr int S  = (GROUP==0) ? 16 : (GROUP==1) ? 64 : 256;
    constexpr int GB = 256 / S;
    __shared__ float Kl[256*32];
    __shared__ float Vl[256*32];
    const int t = threadIdx.x;
    const int bq0 = blockIdx.x * GB;
    {   // stage: thread t owns row r=t of K and V (match_batch gather folded in)
        const int r = t;
        const int g = r / S, j = r % S;
        const int bq = bq0 + g;
        int krow, vrow;
        if constexpr (GROUP == 0) {
            krow = (bq >> 2)*64  + (j << 2) + (bq & 3);
            vrow = (bq >> 4)*256 + (j << 4) + (bq & 15);
        } else if constexpr (GROUP == 1) {
            krow = (bq >> 2)*256 + (j << 2) + (bq & 3);
            vrow = ((bq << 2) + (j & 3))*16 + (j >> 2);
        } else {
            krow = ((bq << 4) + (j & 15))*16 + (j >> 4);
            vrow = ((bq << 2) + (j & 3))*64 + (j >> 2);
        }
        const float4* ksr = reinterpret_cast<const float4*>(Ks + (size_t)krow*32);
        const float4* vsr = reinterpret_cast<const float4*>(Vs + (size_t)vrow*32);
        float4* kd = reinterpret_cast<float4*>(Kl + r*32);
        float4* vd = reinterpret_cast<float4*>(Vl + r*32);
        #pragma unroll
        for (int f = 0; f < 8; ++f) {
            int fs = f ^ (r & 7);   // bank-spread write order (identity layout)
            kd[fs] = ksr[fs];
            vd[fs] = vsr[fs];
        }
    }
    const int g  = t / S;
    const int sq = t % S;
    const int bq = bq0 + g;
    float4 qf[8];
    {
        const float4* qs = reinterpret_cast<const float4*>(Q + ((size_t)bq*S + sq)*32);
        #pragma unroll
        for (int f = 0; f < 8; ++f) qf[f] = qs[f];
    }
    __syncthreads();
    const float4* Kr = reinterpret_cast<const float4*>(Kl) + g*S*8;
    const float4* Vr = reinterpret_cast<const float4*>(Vl) + g*S*8;
    float m = -1e30f, l = 0.f;
    float4 ot[8];
    #pragma unroll
    for (int f = 0; f < 8; ++f) ot[f] = make_float4(0.f,0.f,0.f,0.f);
    for (int j = 0; j < S; ++j) {
        const float4* kr = Kr + j*8;
        float s0=0.f, s1=0.f, s2=0.f, s3=0.f;
        #pragma unroll
        for (int f = 0; f < 8; ++f) {
            float4 kf = kr[f];
            s0 = fmaf(qf[f].x, kf.x, s0);
            s1 = fmaf(qf[f].y, kf.y, s1);
            s2 = fmaf(qf[f].z, kf.z, s2);
            s3 = fmaf(qf[f].w, kf.w, s3);
        }
        float s = (s0+s1)+(s2+s3);
        const float4* vr = Vr + j*8;
        if (s <= m) {               // common path: no rescale
            float p = __expf(s - m);
            l += p;
            #pragma unroll
            for (int f = 0; f < 8; ++f) {
                float4 vf = vr[f];
                ot[f].x = fmaf(p, vf.x, ot[f].x);
                ot[f].y = fmaf(p, vf.y, ot[f].y);
                ot[f].z = fmaf(p, vf.z, ot[f].z);
                ot[f].w = fmaf(p, vf.w, ot[f].w);
            }
        } else {                    // new max: rescale, p = 1
            float sc = __expf(m - s);
            m = s;
            l = fmaf(l, sc, 1.f);
            #pragma unroll
            for (int f = 0; f < 8; ++f) {
                float4 vf = vr[f];
                ot[f].x = fmaf(ot[f].x, sc, vf.x);
                ot[f].y = fmaf(ot[f].y, sc, vf.y);
                ot[f].z = fmaf(ot[f].z, sc, vf.z);
                ot[f].w = fmaf(ot[f].w, sc, vf.w);
            }
        }
    }
    float invl = 1.f / l;
    float4* od = reinterpret_cast<float4*>(O + ((size_t)bq*S + sq)*32);
    #pragma unroll
    for (int f = 0; f < 8; ++f) {
        float4 r4;
        r4.x = ot[f].x * invl; r4.y = ot[f].y * invl;
        r4.z = ot[f].z * invl; r4.w = ot[f].w * invl;
        od[f] = r4;
    }
}

__global__ __launch_bounds__(256) void k_conv_out(
    const float* __restrict__ o0, const float* __restrict__ o1,
    const float* __restrict__ o2, const float* __restrict__ w_out,
    const float* __restrict__ b_out, float* __restrict__ out)
{
    __shared__ float ys[96*64];     // [cc][px]
    __shared__ float wl[96*97];
    const int t = threadIdx.x;
    const int pxb = (t & 15) * 4;
    const int og  = t >> 4;          // 16 groups x 6 outputs
    const int pixbase = blockIdx.x * 64;
    const int b   = pixbase >> 16;
    const int rem = pixbase & 65535;
    const int hh  = rem >> 8;
    const int ww0 = rem & 255;

    for (int k = 0; k < 36; ++k) {
        int idx = k*256 + t;
        int o = idx / 96, c = idx - o*96;
        wl[o*97 + c] = w_out[idx];
    }
    if (t < 192) {   // gather: thread = (scale i, pixel px), unwindow+roll folded in
        const int i  = t >> 6;
        const int px = t & 63;
        const int lg = 2 + i;
        const int ws = 1 << lg;
        const int sft = ws >> 1;
        const int nblk = 256 >> lg;
        int h = (hh - sft) & 255;
        int w = (ww0 + px - sft) & 255;
        int nb = (b*nblk + (h >> lg))*nblk + (w >> lg);
        int roff = nb*(ws*ws) + (h & (ws-1))*ws + (w & (ws-1));
        const float* src = (i==0 ? o0 : i==1 ? o1 : o2) + (size_t)roff*32;
        float* dst = &ys[(i*32)*64 + px];
        const float4* s4 = reinterpret_cast<const float4*>(src);
        float4 rv[8];
        #pragma unroll
        for (int f = 0; f < 8; ++f) rv[f] = s4[f];
        #pragma unroll
        for (int f = 0; f < 8; ++f) {
            dst[(f*4+0)*64] = rv[f].x;
            dst[(f*4+1)*64] = rv[f].y;
            dst[(f*4+2)*64] = rv[f].z;
            dst[(f*4+3)*64] = rv[f].w;
        }
    }
    __syncthreads();

    float acc[4][6];
    #pragma unroll
    for (int p = 0; p < 4; ++p)
        #pragma unroll
        for (int j = 0; j < 6; ++j) acc[p][j] = b_out[og*6 + j];
    for (int c = 0; c < 96; ++c) {
        float4 ya = *reinterpret_cast<const float4*>(&ys[c*64 + pxb]);
        #pragma unroll
        for (int j = 0; j < 6; ++j) {
            float wgt = wl[(og*6 + j)*97 + c];
            acc[0][j] = fmaf(wgt, ya.x, acc[0][j]);
            acc[1][j] = fmaf(wgt, ya.y, acc[1][j]);
            acc[2][j] = fmaf(wgt, ya.z, acc[2][j]);
            acc[3][j] = fmaf(wgt, ya.w, acc[3][j]);
        }
    }
    #pragma unroll
    for (int j = 0; j < 6; ++j) {
        int o = og*6 + j;
        float4 vv;
        vv.x = acc[0][j]; vv.y = acc[1][j]; vv.z = acc[2][j]; vv.w = acc[3][j];
        *reinterpret_cast<float4*>(out + ((size_t)(b*96 + o))*65536 + rem + pxb) = vv;
    }
}

extern "C" void kernel_launch(void* const* d_in, const int* in_sizes, int n_in,
                              void* d_out, int out_size, void* d_ws, size_t ws_size,
                              hipStream_t stream)
{
    const float* x     = (const float*)d_in[0];
    const float* w_in  = (const float*)d_in[1];
    const float* b_in  = (const float*)d_in[2];
    const float* gma   = (const float*)d_in[3];
    const float* bta   = (const float*)d_in[4];
    const float* mu    = (const float*)d_in[5];
    const float* var   = (const float*)d_in[6];
    const float* w_out = (const float*)d_in[7];
    const float* b_out = (const float*)d_in[8];
    float* out = (float*)d_out;

    float* W = (float*)d_ws;
    const size_t M = 16777216;   // 2^24 floats per buffer
    float *q0 = W,       *v0 = W +   M, *q1 = W + 2*M,
          *v1 = W + 3*M, *q2 = W + 4*M, *v2 = W + 5*M;

    k_conv_in<<<8192, 256, 0, stream>>>(x, w_in, b_in, gma, bta, mu, var,
                                        q0, v0, q1, v1, q2, v2);
    // outputs written in-place over each attention's V buffer
    k_attn<0><<<2048, 256, 0, stream>>>(q0, q1, v2, v2);
    k_attn<1><<<2048, 256, 0, stream>>>(q1, q2, v0, v0);
    k_attn<2><<<2048, 256, 0, stream>>>(q2, q0, v1, v1);
    k_conv_out<<<8192, 256, 0, stream>>>(v2, v0, v1, w_out, b_out, out);
}

// Round 4
// 685.399 us; speedup vs baseline: 1.6717x; 1.6717x over previous
//
#include <hip/hip_runtime.h>

// GMSA r4: conv_in(f32 compute, f16 out) | 3x MFMA-f16 flash attention | conv_out(f16 in)
// d_ws: 6 f16 buffers of 2^24 elems: q0 v0 q1 v1 q2 v2 (201 MB).
// Attention output written IN-PLACE over its V buffer (block-local bijection).
// r4 fix: PER-ROW softmax max (was 4-row group max -> fp16 P underflow when a
// row's max sits >~16 below the group max -> O row ~0, absmax ~3).

typedef _Float16 f16x8 __attribute__((ext_vector_type(8)));
typedef _Float16 f16x4 __attribute__((ext_vector_type(4)));
typedef float    f32x4 __attribute__((ext_vector_type(4)));

__global__ __launch_bounds__(256) void k_conv_in(
    const float* __restrict__ x, const float* __restrict__ w_in,
    const float* __restrict__ b_in, const float* __restrict__ gma,
    const float* __restrict__ bta, const float* __restrict__ mu,
    const float* __restrict__ var,
    _Float16* __restrict__ q0, _Float16* __restrict__ v0,
    _Float16* __restrict__ q1, _Float16* __restrict__ v1,
    _Float16* __restrict__ q2, _Float16* __restrict__ v2)
{
    __shared__ float xs[96*64];     // [c][px]
    __shared__ float wl[192*49];
    __shared__ float invs[192];
    __shared__ float bias[192];
    const int t    = threadIdx.x;
    const int lane = t & 63;
    const int wv   = t >> 6;
    const int pxb  = (t & 15) * 4;
    const int og   = t >> 4;

    if (t < 192) {
        float iv = gma[t] * rsqrtf(var[t] + 1e-5f);
        invs[t] = iv;
        bias[t] = b_in[t]*iv + bta[t] - mu[t]*iv;
    }

    const int pixbase = blockIdx.x * 64;
    const int b   = pixbase >> 16;
    const int rem = pixbase & 65535;
    const int hh  = rem >> 8;
    const int ww0 = rem & 255;

    {
        const float* xb = x + (size_t)b*96*65536 + rem;
        #pragma unroll
        for (int k = 0; k < 24; ++k) {
            int c = k*4 + wv;
            xs[c*64 + lane] = xb[(size_t)c*65536 + lane];
        }
    }

    int ro[3][4];
    #pragma unroll
    for (int i = 0; i < 3; ++i) {
        const int lg = 2 + i;
        const int ws = 1 << lg;
        const int sft = ws >> 1;
        const int nblk = 256 >> lg;
        int h  = (hh - sft) & 255;
        int hb = h >> lg, hr = h & (ws-1);
        int nbrow = (b*nblk + hb)*nblk;
        #pragma unroll
        for (int p = 0; p < 4; ++p) {
            int w = (ww0 + pxb + p - sft) & 255;
            ro[i][p] = (nbrow + (w >> lg))*(ws*ws) + hr*ws + (w & (ws-1));
        }
    }

    float acc[4][12];
    #pragma unroll
    for (int p = 0; p < 4; ++p)
        #pragma unroll
        for (int j = 0; j < 12; ++j) acc[p][j] = 0.f;

    for (int cp = 0; cp < 2; ++cp) {
        __syncthreads();
        for (int k = 0; k < 36; ++k) {
            int idx = k*256 + t;
            int o = idx / 48, ch = idx - o*48;
            wl[o*49 + ch] = w_in[o*96 + cp*48 + ch];
        }
        __syncthreads();
        const int cb = cp*48;
        for (int c = 0; c < 48; ++c) {
            float4 xa = *reinterpret_cast<const float4*>(&xs[(cb + c)*64 + pxb]);
            #pragma unroll
            for (int j = 0; j < 12; ++j) {
                float wgt = wl[(og*12 + j)*49 + c];
                acc[0][j] = fmaf(wgt, xa.x, acc[0][j]);
                acc[1][j] = fmaf(wgt, xa.y, acc[1][j]);
                acc[2][j] = fmaf(wgt, xa.z, acc[2][j]);
                acc[3][j] = fmaf(wgt, xa.w, acc[3][j]);
            }
        }
    }

    #pragma unroll
    for (int j4 = 0; j4 < 12; j4 += 4) {
        const int o   = og*12 + j4;
        const int sc  = o >> 6;
        const int oc  = o & 63;
        const int c32 = oc & 31;
        const bool isv = (oc & 32) != 0;
        _Float16* tb = (sc == 0) ? (isv ? v0 : q0)
                     : (sc == 1) ? (isv ? v1 : q1)
                                 : (isv ? v2 : q2);
        #pragma unroll
        for (int p = 0; p < 4; ++p) {
            int roff = (sc == 0) ? ro[0][p] : (sc == 1) ? ro[1][p] : ro[2][p];
            f16x4 hv;
            hv[0] = (_Float16)fmaf(acc[p][j4+0], invs[o+0], bias[o+0]);
            hv[1] = (_Float16)fmaf(acc[p][j4+1], invs[o+1], bias[o+1]);
            hv[2] = (_Float16)fmaf(acc[p][j4+2], invs[o+2], bias[o+2]);
            hv[3] = (_Float16)fmaf(acc[p][j4+3], invs[o+3], bias[o+3]);
            *reinterpret_cast<f16x4*>(tb + (size_t)roff*32 + c32) = hv;
        }
    }
}

// Flash attention, fp16 MFMA 16x16x32, d=32. Block = 256 Q rows, 4 waves x 64 rows.
// GROUP 0: nb=32768,S=16  Q=q0 K=q1 V=v2 | GROUP 1: nb=8192,S=64 Q=q1 K=q2 V=v0
// GROUP 2: nb=2048, S=256 Q=q2 K=q0 V=v1
template<int GROUP>
__global__ __launch_bounds__(256) void k_attn(
    const _Float16* __restrict__ Q, const _Float16* __restrict__ Ks,
    const _Float16* Vs, _Float16* O)
{
    constexpr int S   = (GROUP==0) ? 16 : (GROUP==1) ? 64 : 256;
    constexpr int GB  = 256 / S;
    constexpr int KT  = (S < 32) ? 16 : 32;
    constexpr int NT  = S / KT;
    constexpr int CBS = KT / 16;

    __shared__ uint4    Kl[4*256];          // chunk j (8 f16 of d) of key k at [j*256+k]
    __shared__ _Float16 Vt[32*264 + 8];     // V^T: [d][key], stride 264 (+pad)
    __shared__ _Float16 Pl[4][64*40];       // per-wave P, row stride 40 f16

    const int t = threadIdx.x;
    {   // stage K (chunk-scattered) + V (transposed); row r = t, match_batch folded in
        const int g = t / S, j = t % S;
        const int bq = blockIdx.x * GB + g;
        int krow, vrow;
        if constexpr (GROUP == 0) {
            krow = (bq >> 2)*64  + (j << 2) + (bq & 3);
            vrow = (bq >> 4)*256 + (j << 4) + (bq & 15);
        } else if constexpr (GROUP == 1) {
            krow = (bq >> 2)*256 + (j << 2) + (bq & 3);
            vrow = ((bq << 2) + (j & 3))*16 + (j >> 2);
        } else {
            krow = ((bq << 4) + (j & 15))*16 + (j >> 4);
            vrow = ((bq << 2) + (j & 3))*64 + (j >> 2);
        }
        const uint4* ks = reinterpret_cast<const uint4*>(Ks + (size_t)krow*32);
        uint4 ka = ks[0], kb = ks[1], kc = ks[2], kd = ks[3];
        Kl[0*256 + t] = ka; Kl[1*256 + t] = kb;
        Kl[2*256 + t] = kc; Kl[3*256 + t] = kd;
        union { uint4 u4[4]; _Float16 h[32]; } vb;
        const uint4* vs = reinterpret_cast<const uint4*>(Vs + (size_t)vrow*32);
        vb.u4[0] = vs[0]; vb.u4[1] = vs[1]; vb.u4[2] = vs[2]; vb.u4[3] = vs[3];
        #pragma unroll
        for (int d = 0; d < 32; ++d) Vt[d*264 + t] = vb.h[d];
        // zero Vt pad keys 256..263 (all 32 d-rows) + 8-elem tail: S==16 PV edge
        // reads them (x P=0). Garbage here -> 0*NaN = NaN.
        Vt[(t >> 3)*264 + 256 + (t & 7)] = (_Float16)0.f;
        if (t < 8) Vt[32*264 + t] = (_Float16)0.f;
    }
    const int wv = t >> 6, ln = t & 63;
    const int lo = ln & 15, hi = ln >> 4;
    _Float16* Pw = Pl[wv];
    if constexpr (S == 16) {    // zero pad-cols 16..31 once (stay zero)
        uint* pw32 = reinterpret_cast<uint*>(Pw);
        #pragma unroll
        for (int k2 = 0; k2 < 8; ++k2) {
            int idx = ln + k2*64;
            pw32[(idx >> 3)*20 + 8 + (idx & 7)] = 0u;
        }
    }
    __syncthreads();

    const int rowbase = blockIdx.x*256 + wv*64;
    f16x8 qf[4];
    #pragma unroll
    for (int rb = 0; rb < 4; ++rb) {
        uint4 qv = *reinterpret_cast<const uint4*>(
            Q + ((size_t)(rowbase + rb*16 + lo))*32 + hi*8);
        qf[rb] = __builtin_bit_cast(f16x8, qv);
    }

    f32x4 ofr[4][2];
    float m[4][4], ls[4][4];
    #pragma unroll
    for (int rb = 0; rb < 4; ++rb) {
        #pragma unroll
        for (int r = 0; r < 4; ++r) { m[rb][r] = -1e30f; ls[rb][r] = 0.f; }
        ofr[rb][0] = f32x4{0.f,0.f,0.f,0.f};
        ofr[rb][1] = f32x4{0.f,0.f,0.f,0.f};
    }
    const f32x4 zf = f32x4{0.f,0.f,0.f,0.f};

    for (int tt = 0; tt < NT; ++tt) {
        f32x4 sf[4][CBS];
        if constexpr (S == 16) {
            #pragma unroll
            for (int rb = 0; rb < 4; ++rb) {
                int key = wv*64 + rb*16 + lo;
                f16x8 bk = __builtin_bit_cast(f16x8, Kl[hi*256 + key]);
                sf[rb][0] = __builtin_amdgcn_mfma_f32_16x16x32_f16(qf[rb], bk, zf, 0,0,0);
            }
        } else {
            f16x8 bk[CBS];
            const int wb = (S == 64) ? wv*64 : 0;
            #pragma unroll
            for (int cb = 0; cb < CBS; ++cb) {
                int key = wb + tt*KT + cb*16 + lo;
                bk[cb] = __builtin_bit_cast(f16x8, Kl[hi*256 + key]);
            }
            #pragma unroll
            for (int rb = 0; rb < 4; ++rb)
                #pragma unroll
                for (int cb = 0; cb < CBS; ++cb)
                    sf[rb][cb] = __builtin_amdgcn_mfma_f32_16x16x32_f16(qf[rb], bk[cb], zf, 0,0,0);
        }

        #pragma unroll
        for (int rb = 0; rb < 4; ++rb) {
            // per-ROW online max: row hi*4+r <-> reg r; keys live across lo lanes
            #pragma unroll
            for (int r = 0; r < 4; ++r) {
                float tm = sf[rb][0][r];
                #pragma unroll
                for (int cb = 1; cb < CBS; ++cb) tm = fmaxf(tm, sf[rb][cb][r]);
                tm = fmaxf(tm, __shfl_xor(tm, 1));
                tm = fmaxf(tm, __shfl_xor(tm, 2));
                tm = fmaxf(tm, __shfl_xor(tm, 4));
                tm = fmaxf(tm, __shfl_xor(tm, 8));
                float mn = fmaxf(m[rb][r], tm);
                float sc = __expf(m[rb][r] - mn);
                m[rb][r] = mn;
                ls[rb][r] *= sc;
                ofr[rb][0][r] *= sc;
                ofr[rb][1][r] *= sc;
                #pragma unroll
                for (int cb = 0; cb < CBS; ++cb) {
                    float p = __expf(sf[rb][cb][r] - mn);
                    ls[rb][r] += p;
                    Pw[(rb*16 + hi*4 + r)*40 + cb*16 + lo] = (_Float16)p;
                }
            }
        }

        #pragma unroll
        for (int rb = 0; rb < 4; ++rb) {
            f16x8 pa = *reinterpret_cast<const f16x8*>(Pw + (rb*16 + lo)*40 + hi*8);
            const int wb = (S == 16) ? wv*64 + rb*16 : (S == 64) ? wv*64 : 0;
            const int key0 = wb + tt*KT + hi*8;
            #pragma unroll
            for (int dcb = 0; dcb < 2; ++dcb) {
                f16x8 bv = *reinterpret_cast<const f16x8*>(Vt + (dcb*16 + lo)*264 + key0);
                ofr[rb][dcb] = __builtin_amdgcn_mfma_f32_16x16x32_f16(pa, bv, ofr[rb][dcb], 0,0,0);
            }
        }
    }

    #pragma unroll
    for (int rb = 0; rb < 4; ++rb) {
        #pragma unroll
        for (int r = 0; r < 4; ++r) {
            float v = ls[rb][r];
            v += __shfl_xor(v, 1);
            v += __shfl_xor(v, 2);
            v += __shfl_xor(v, 4);
            v += __shfl_xor(v, 8);
            ls[rb][r] = 1.f / v;
        }
        #pragma unroll
        for (int dcb = 0; dcb < 2; ++dcb)
            #pragma unroll
            for (int r = 0; r < 4; ++r) {
                float ov = ofr[rb][dcb][r] * ls[rb][r];
                int row = rowbase + rb*16 + hi*4 + r;
                O[(size_t)row*32 + dcb*16 + lo] = (_Float16)ov;
            }
    }
}

__global__ __launch_bounds__(256) void k_conv_out(
    const _Float16* __restrict__ o0, const _Float16* __restrict__ o1,
    const _Float16* __restrict__ o2, const float* __restrict__ w_out,
    const float* __restrict__ b_out, float* __restrict__ out)
{
    __shared__ float ys[96*64];
    __shared__ float wl[96*97];
    const int t = threadIdx.x;
    const int pxb = (t & 15) * 4;
    const int og  = t >> 4;
    const int pixbase = blockIdx.x * 64;
    const int b   = pixbase >> 16;
    const int rem = pixbase & 65535;
    const int hh  = rem >> 8;
    const int ww0 = rem & 255;

    for (int k = 0; k < 36; ++k) {
        int idx = k*256 + t;
        int o = idx / 96, c = idx - o*96;
        wl[o*97 + c] = w_out[idx];
    }
    if (t < 192) {
        const int i  = t >> 6;
        const int px = t & 63;
        const int lg = 2 + i;
        const int ws = 1 << lg;
        const int sft = ws >> 1;
        const int nblk = 256 >> lg;
        int h = (hh - sft) & 255;
        int w = (ww0 + px - sft) & 255;
        int nb = (b*nblk + (h >> lg))*nblk + (w >> lg);
        int roff = nb*(ws*ws) + (h & (ws-1))*ws + (w & (ws-1));
        const _Float16* src = (i==0 ? o0 : i==1 ? o1 : o2) + (size_t)roff*32;
        union { uint4 u4[4]; _Float16 h16[32]; } vb;
        const uint4* s4 = reinterpret_cast<const uint4*>(src);
        vb.u4[0] = s4[0]; vb.u4[1] = s4[1]; vb.u4[2] = s4[2]; vb.u4[3] = s4[3];
        float* dst = &ys[(i*32)*64 + px];
        #pragma unroll
        for (int f = 0; f < 32; ++f) dst[f*64] = (float)vb.h16[f];
    }
    __syncthreads();

    float acc[4][6];
    #pragma unroll
    for (int p = 0; p < 4; ++p)
        #pragma unroll
        for (int j = 0; j < 6; ++j) acc[p][j] = b_out[og*6 + j];
    for (int c = 0; c < 96; ++c) {
        float4 ya = *reinterpret_cast<const float4*>(&ys[c*64 + pxb]);
        #pragma unroll
        for (int j = 0; j < 6; ++j) {
            float wgt = wl[(og*6 + j)*97 + c];
            acc[0][j] = fmaf(wgt, ya.x, acc[0][j]);
            acc[1][j] = fmaf(wgt, ya.y, acc[1][j]);
            acc[2][j] = fmaf(wgt, ya.z, acc[2][j]);
            acc[3][j] = fmaf(wgt, ya.w, acc[3][j]);
        }
    }
    #pragma unroll
    for (int j = 0; j < 6; ++j) {
        int o = og*6 + j;
        float4 vv;
        vv.x = acc[0][j]; vv.y = acc[1][j]; vv.z = acc[2][j]; vv.w = acc[3][j];
        *reinterpret_cast<float4*>(out + ((size_t)(b*96 + o))*65536 + rem + pxb) = vv;
    }
}

extern "C" void kernel_launch(void* const* d_in, const int* in_sizes, int n_in,
                              void* d_out, int out_size, void* d_ws, size_t ws_size,
                              hipStream_t stream)
{
    const float* x     = (const float*)d_in[0];
    const float* w_in  = (const float*)d_in[1];
    const float* b_in  = (const float*)d_in[2];
    const float* gma   = (const float*)d_in[3];
    const float* bta   = (const float*)d_in[4];
    const float* mu    = (const float*)d_in[5];
    const float* var   = (const float*)d_in[6];
    const float* w_out = (const float*)d_in[7];
    const float* b_out = (const float*)d_in[8];
    float* out = (float*)d_out;

    _Float16* W = (_Float16*)d_ws;
    const size_t M = 16777216;
    _Float16 *q0 = W,       *v0 = W +   M, *q1 = W + 2*M,
             *v1 = W + 3*M, *q2 = W + 4*M, *v2 = W + 5*M;

    k_conv_in<<<8192, 256, 0, stream>>>(x, w_in, b_in, gma, bta, mu, var,
                                        q0, v0, q1, v1, q2, v2);
    k_attn<0><<<2048, 256, 0, stream>>>(q0, q1, v2, v2);
    k_attn<1><<<2048, 256, 0, stream>>>(q1, q2, v0, v0);
    k_attn<2><<<2048, 256, 0, stream>>>(q2, q0, v1, v1);
    k_conv_out<<<8192, 256, 0, stream>>>(v2, v0, v1, w_out, b_out, out);
}

// Round 5
// 491.190 us; speedup vs baseline: 2.3326x; 1.3954x over previous
//
#include <hip/hip_runtime.h>

// GMSA r5: MFMA everywhere. conv_in/conv_out become f16 MFMA GEMMs (BN inv
// folded into A-frag weights; epilogue = +bias). Attention unchanged from r4.
// d_ws: 6 f16 buffers of 2^24 elems: q0 v0 q1 v1 q2 v2.

typedef _Float16 f16x8 __attribute__((ext_vector_type(8)));
typedef _Float16 f16x4 __attribute__((ext_vector_type(4)));
typedef float    f32x4 __attribute__((ext_vector_type(4)));

__device__ inline f16x8 pack8(float4 a, float4 b) {
    f16x8 r;
    r[0]=(_Float16)a.x; r[1]=(_Float16)a.y; r[2]=(_Float16)a.z; r[3]=(_Float16)a.w;
    r[4]=(_Float16)b.x; r[5]=(_Float16)b.y; r[6]=(_Float16)b.z; r[7]=(_Float16)b.w;
    return r;
}

// conv_in as MFMA GEMM: D[192 o][64 px] = (W*inv)[o][96 c] x[c][px] + bias[o]
// then windowed scatter (roll folded) to q/v f16 buffers.
__global__ __launch_bounds__(256) void k_conv_in(
    const float* __restrict__ x, const float* __restrict__ w_in,
    const float* __restrict__ b_in, const float* __restrict__ gma,
    const float* __restrict__ bta, const float* __restrict__ mu,
    const float* __restrict__ var,
    _Float16* __restrict__ q0, _Float16* __restrict__ v0,
    _Float16* __restrict__ q1, _Float16* __restrict__ v1,
    _Float16* __restrict__ q2, _Float16* __restrict__ v2)
{
    __shared__ float xs[96*65];     // [c][px], pad 65 (frag reads exactly 2-way)
    __shared__ float invs[192];
    __shared__ float bias[192];
    const int t  = threadIdx.x;
    const int wv = t >> 6, ln = t & 63;
    const int lo = ln & 15, hi = ln >> 4;

    if (t < 192) {
        float iv = gma[t] * rsqrtf(var[t] + 1e-5f);
        invs[t] = iv;
        bias[t] = b_in[t]*iv + bta[t] - mu[t]*iv;
    }

    const int pixbase = blockIdx.x * 64;
    const int b   = pixbase >> 16;
    const int rem = pixbase & 65535;
    const int hh  = rem >> 8;
    const int ww0 = rem & 255;

    {   // stage x tile f32 [96][65], coalesced float4
        const float* xb = x + (size_t)b*96*65536 + rem;
        #pragma unroll
        for (int pass = 0; pass < 6; ++pass) {
            int idx = pass*256 + t;
            int c   = idx >> 4;
            int p4  = (idx & 15) << 2;
            float4 v = *reinterpret_cast<const float4*>(xb + (size_t)c*65536 + p4);
            *reinterpret_cast<float4*>(&xs[c*65 + p4]) = v;
        }
    }
    __syncthreads();

    // A frags: rows wv*48+rf*16+lo, k = ks*32+hi*8..+7, scaled by invs[row]
    f16x8 af[3][3];
    #pragma unroll
    for (int rf = 0; rf < 3; ++rf) {
        const int row = wv*48 + rf*16 + lo;
        const float iv = invs[row];
        #pragma unroll
        for (int ks = 0; ks < 3; ++ks) {
            const float* wp = w_in + row*96 + ks*32 + hi*8;
            float4 wa = *reinterpret_cast<const float4*>(wp);
            float4 wb = *reinterpret_cast<const float4*>(wp + 4);
            wa.x*=iv; wa.y*=iv; wa.z*=iv; wa.w*=iv;
            wb.x*=iv; wb.y*=iv; wb.z*=iv; wb.w*=iv;
            af[rf][ks] = pack8(wa, wb);
        }
    }

    f32x4 acc[3][4];
    #pragma unroll
    for (int rf = 0; rf < 3; ++rf)
        #pragma unroll
        for (int cf = 0; cf < 4; ++cf) acc[rf][cf] = f32x4{0.f,0.f,0.f,0.f};

    #pragma unroll
    for (int cf = 0; cf < 4; ++cf) {
        #pragma unroll
        for (int ks = 0; ks < 3; ++ks) {
            const float* bp = &xs[(ks*32 + hi*8)*65 + cf*16 + lo];
            f16x8 bfv;
            #pragma unroll
            for (int e = 0; e < 8; ++e) bfv[e] = (_Float16)bp[e*65];
            #pragma unroll
            for (int rf = 0; rf < 3; ++rf)
                acc[rf][cf] = __builtin_amdgcn_mfma_f32_16x16x32_f16(
                                  af[rf][ks], bfv, acc[rf][cf], 0,0,0);
        }
    }

    // window row offsets for pixel p = cf*16+lo, per scale
    int ro[3][4];
    #pragma unroll
    for (int i = 0; i < 3; ++i) {
        const int lg = 2 + i;
        const int ws = 1 << lg;
        const int sft = ws >> 1;
        const int nblk = 256 >> lg;
        int h  = (hh - sft) & 255;
        int nbrow = (b*nblk + (h >> lg))*nblk;
        int hr = h & (ws-1);
        #pragma unroll
        for (int cf = 0; cf < 4; ++cf) {
            int w = (ww0 + cf*16 + lo - sft) & 255;
            ro[i][cf] = (nbrow + (w >> lg))*(ws*ws) + hr*ws + (w & (ws-1));
        }
    }

    #pragma unroll
    for (int rf = 0; rf < 3; ++rf) {
        const int base = wv*48 + rf*16;        // multiple of 16
        const int o0   = base + hi*4;
        const int sc   = base >> 6;
        const bool isv = (base & 32) != 0;
        const int c32  = o0 & 31;
        float4 bi = *reinterpret_cast<const float4*>(&bias[o0]);
        _Float16* tb = (sc == 0) ? (isv ? v0 : q0)
                     : (sc == 1) ? (isv ? v1 : q1)
                                 : (isv ? v2 : q2);
        #pragma unroll
        for (int cf = 0; cf < 4; ++cf) {
            f16x4 hv;
            hv[0] = (_Float16)(acc[rf][cf][0] + bi.x);
            hv[1] = (_Float16)(acc[rf][cf][1] + bi.y);
            hv[2] = (_Float16)(acc[rf][cf][2] + bi.z);
            hv[3] = (_Float16)(acc[rf][cf][3] + bi.w);
            *reinterpret_cast<f16x4*>(tb + (size_t)ro[sc][cf]*32 + c32) = hv;
        }
    }
}

// Flash attention, fp16 MFMA 16x16x32, d=32 (unchanged from r4).
template<int GROUP>
__global__ __launch_bounds__(256) void k_attn(
    const _Float16* __restrict__ Q, const _Float16* __restrict__ Ks,
    const _Float16* Vs, _Float16* O)
{
    constexpr int S   = (GROUP==0) ? 16 : (GROUP==1) ? 64 : 256;
    constexpr int GB  = 256 / S;
    constexpr int KT  = (S < 32) ? 16 : 32;
    constexpr int NT  = S / KT;
    constexpr int CBS = KT / 16;

    __shared__ uint4    Kl[4*256];
    __shared__ _Float16 Vt[32*264 + 8];
    __shared__ _Float16 Pl[4][64*40];

    const int t = threadIdx.x;
    {
        const int g = t / S, j = t % S;
        const int bq = blockIdx.x * GB + g;
        int krow, vrow;
        if constexpr (GROUP == 0) {
            krow = (bq >> 2)*64  + (j << 2) + (bq & 3);
            vrow = (bq >> 4)*256 + (j << 4) + (bq & 15);
        } else if constexpr (GROUP == 1) {
            krow = (bq >> 2)*256 + (j << 2) + (bq & 3);
            vrow = ((bq << 2) + (j & 3))*16 + (j >> 2);
        } else {
            krow = ((bq << 4) + (j & 15))*16 + (j >> 4);
            vrow = ((bq << 2) + (j & 3))*64 + (j >> 2);
        }
        const uint4* ks = reinterpret_cast<const uint4*>(Ks + (size_t)krow*32);
        uint4 ka = ks[0], kb = ks[1], kc = ks[2], kd = ks[3];
        Kl[0*256 + t] = ka; Kl[1*256 + t] = kb;
        Kl[2*256 + t] = kc; Kl[3*256 + t] = kd;
        union { uint4 u4[4]; _Float16 h[32]; } vb;
        const uint4* vs = reinterpret_cast<const uint4*>(Vs + (size_t)vrow*32);
        vb.u4[0] = vs[0]; vb.u4[1] = vs[1]; vb.u4[2] = vs[2]; vb.u4[3] = vs[3];
        #pragma unroll
        for (int d = 0; d < 32; ++d) Vt[d*264 + t] = vb.h[d];
        Vt[(t >> 3)*264 + 256 + (t & 7)] = (_Float16)0.f;
        if (t < 8) Vt[32*264 + t] = (_Float16)0.f;
    }
    const int wv = t >> 6, ln = t & 63;
    const int lo = ln & 15, hi = ln >> 4;
    _Float16* Pw = Pl[wv];
    if constexpr (S == 16) {
        uint* pw32 = reinterpret_cast<uint*>(Pw);
        #pragma unroll
        for (int k2 = 0; k2 < 8; ++k2) {
            int idx = ln + k2*64;
            pw32[(idx >> 3)*20 + 8 + (idx & 7)] = 0u;
        }
    }
    __syncthreads();

    const int rowbase = blockIdx.x*256 + wv*64;
    f16x8 qf[4];
    #pragma unroll
    for (int rb = 0; rb < 4; ++rb) {
        uint4 qv = *reinterpret_cast<const uint4*>(
            Q + ((size_t)(rowbase + rb*16 + lo))*32 + hi*8);
        qf[rb] = __builtin_bit_cast(f16x8, qv);
    }

    f32x4 ofr[4][2];
    float m[4][4], ls[4][4];
    #pragma unroll
    for (int rb = 0; rb < 4; ++rb) {
        #pragma unroll
        for (int r = 0; r < 4; ++r) { m[rb][r] = -1e30f; ls[rb][r] = 0.f; }
        ofr[rb][0] = f32x4{0.f,0.f,0.f,0.f};
        ofr[rb][1] = f32x4{0.f,0.f,0.f,0.f};
    }
    const f32x4 zf = f32x4{0.f,0.f,0.f,0.f};

    for (int tt = 0; tt < NT; ++tt) {
        f32x4 sf[4][CBS];
        if constexpr (S == 16) {
            #pragma unroll
            for (int rb = 0; rb < 4; ++rb) {
                int key = wv*64 + rb*16 + lo;
                f16x8 bk = __builtin_bit_cast(f16x8, Kl[hi*256 + key]);
                sf[rb][0] = __builtin_amdgcn_mfma_f32_16x16x32_f16(qf[rb], bk, zf, 0,0,0);
            }
        } else {
            f16x8 bk[CBS];
            const int wb = (S == 64) ? wv*64 : 0;
            #pragma unroll
            for (int cb = 0; cb < CBS; ++cb) {
                int key = wb + tt*KT + cb*16 + lo;
                bk[cb] = __builtin_bit_cast(f16x8, Kl[hi*256 + key]);
            }
            #pragma unroll
            for (int rb = 0; rb < 4; ++rb)
                #pragma unroll
                for (int cb = 0; cb < CBS; ++cb)
                    sf[rb][cb] = __builtin_amdgcn_mfma_f32_16x16x32_f16(qf[rb], bk[cb], zf, 0,0,0);
        }

        #pragma unroll
        for (int rb = 0; rb < 4; ++rb) {
            #pragma unroll
            for (int r = 0; r < 4; ++r) {
                float tm = sf[rb][0][r];
                #pragma unroll
                for (int cb = 1; cb < CBS; ++cb) tm = fmaxf(tm, sf[rb][cb][r]);
                tm = fmaxf(tm, __shfl_xor(tm, 1));
                tm = fmaxf(tm, __shfl_xor(tm, 2));
                tm = fmaxf(tm, __shfl_xor(tm, 4));
                tm = fmaxf(tm, __shfl_xor(tm, 8));
                float mn = fmaxf(m[rb][r], tm);
                float sc = __expf(m[rb][r] - mn);
                m[rb][r] = mn;
                ls[rb][r] *= sc;
                ofr[rb][0][r] *= sc;
                ofr[rb][1][r] *= sc;
                #pragma unroll
                for (int cb = 0; cb < CBS; ++cb) {
                    float p = __expf(sf[rb][cb][r] - mn);
                    ls[rb][r] += p;
                    Pw[(rb*16 + hi*4 + r)*40 + cb*16 + lo] = (_Float16)p;
                }
            }
        }

        #pragma unroll
        for (int rb = 0; rb < 4; ++rb) {
            f16x8 pa = *reinterpret_cast<const f16x8*>(Pw + (rb*16 + lo)*40 + hi*8);
            const int wb = (S == 16) ? wv*64 + rb*16 : (S == 64) ? wv*64 : 0;
            const int key0 = wb + tt*KT + hi*8;
            #pragma unroll
            for (int dcb = 0; dcb < 2; ++dcb) {
                f16x8 bv = *reinterpret_cast<const f16x8*>(Vt + (dcb*16 + lo)*264 + key0);
                ofr[rb][dcb] = __builtin_amdgcn_mfma_f32_16x16x32_f16(pa, bv, ofr[rb][dcb], 0,0,0);
            }
        }
    }

    #pragma unroll
    for (int rb = 0; rb < 4; ++rb) {
        #pragma unroll
        for (int r = 0; r < 4; ++r) {
            float v = ls[rb][r];
            v += __shfl_xor(v, 1);
            v += __shfl_xor(v, 2);
            v += __shfl_xor(v, 4);
            v += __shfl_xor(v, 8);
            ls[rb][r] = 1.f / v;
        }
        #pragma unroll
        for (int dcb = 0; dcb < 2; ++dcb)
            #pragma unroll
            for (int r = 0; r < 4; ++r) {
                float ov = ofr[rb][dcb][r] * ls[rb][r];
                int row = rowbase + rb*16 + hi*4 + r;
                O[(size_t)row*32 + dcb*16 + lo] = (_Float16)ov;
            }
    }
}

// conv_out as MFMA GEMM: D[96 o][64 px] = w_out[o][96 c] y[c][px] + b_out[o]
// y gathered from 3 attention-output buffers (unwindow+roll folded), staged
// transposed f16 [px][104] with b128 writes (c-runs of 32 are contiguous).
__global__ __launch_bounds__(256) void k_conv_out(
    const _Float16* __restrict__ o0, const _Float16* __restrict__ o1,
    const _Float16* __restrict__ o2, const float* __restrict__ w_out,
    const float* __restrict__ b_out, float* __restrict__ out)
{
    __shared__ _Float16 yt[64*104];    // [px][c], stride 104
    const int t  = threadIdx.x;
    const int wv = t >> 6, ln = t & 63;
    const int lo = ln & 15, hi = ln >> 4;
    const int pixbase = blockIdx.x * 64;
    const int b   = pixbase >> 16;
    const int rem = pixbase & 65535;
    const int hh  = rem >> 8;
    const int ww0 = rem & 255;

    if (t < 192) {   // gather: thread = (scale i, pixel px)
        const int i  = t >> 6;
        const int px = t & 63;
        const int lg = 2 + i;
        const int ws = 1 << lg;
        const int sft = ws >> 1;
        const int nblk = 256 >> lg;
        int h = (hh - sft) & 255;
        int w = (ww0 + px - sft) & 255;
        int nb = (b*nblk + (h >> lg))*nblk + (w >> lg);
        int roff = nb*(ws*ws) + (h & (ws-1))*ws + (w & (ws-1));
        const uint4* src = reinterpret_cast<const uint4*>(
            ((i==0 ? o0 : i==1 ? o1 : o2) + (size_t)roff*32));
        uint4 r0 = src[0], r1 = src[1], r2 = src[2], r3 = src[3];
        uint4* dst = reinterpret_cast<uint4*>(&yt[px*104 + i*32]);
        dst[0] = r0; dst[1] = r1; dst[2] = r2; dst[3] = r3;
    }
    __syncthreads();

    // A frags: w_out rows rf*16+lo, k = ks*32+hi*8
    f16x8 af[6][3];
    #pragma unroll
    for (int rf = 0; rf < 6; ++rf)
        #pragma unroll
        for (int ks = 0; ks < 3; ++ks) {
            const float* wp = w_out + (rf*16 + lo)*96 + ks*32 + hi*8;
            float4 wa = *reinterpret_cast<const float4*>(wp);
            float4 wb = *reinterpret_cast<const float4*>(wp + 4);
            af[rf][ks] = pack8(wa, wb);
        }

    f32x4 acc[6];
    #pragma unroll
    for (int rf = 0; rf < 6; ++rf) acc[rf] = f32x4{0.f,0.f,0.f,0.f};

    #pragma unroll
    for (int ks = 0; ks < 3; ++ks) {
        f16x8 bfv = *reinterpret_cast<const f16x8*>(
            &yt[(wv*16 + lo)*104 + ks*32 + hi*8]);
        #pragma unroll
        for (int rf = 0; rf < 6; ++rf)
            acc[rf] = __builtin_amdgcn_mfma_f32_16x16x32_f16(af[rf][ks], bfv, acc[rf], 0,0,0);
    }

    const int px = wv*16 + lo;
    #pragma unroll
    for (int rf = 0; rf < 6; ++rf) {
        const int oo = rf*16 + hi*4;
        float4 bi = *reinterpret_cast<const float4*>(b_out + oo);
        out[((size_t)(b*96 + oo+0))*65536 + rem + px] = acc[rf][0] + bi.x;
        out[((size_t)(b*96 + oo+1))*65536 + rem + px] = acc[rf][1] + bi.y;
        out[((size_t)(b*96 + oo+2))*65536 + rem + px] = acc[rf][2] + bi.z;
        out[((size_t)(b*96 + oo+3))*65536 + rem + px] = acc[rf][3] + bi.w;
    }
}

extern "C" void kernel_launch(void* const* d_in, const int* in_sizes, int n_in,
                              void* d_out, int out_size, void* d_ws, size_t ws_size,
                              hipStream_t stream)
{
    const float* x     = (const float*)d_in[0];
    const float* w_in  = (const float*)d_in[1];
    const float* b_in  = (const float*)d_in[2];
    const float* gma   = (const float*)d_in[3];
    const float* bta   = (const float*)d_in[4];
    const float* mu    = (const float*)d_in[5];
    const float* var   = (const float*)d_in[6];
    const float* w_out = (const float*)d_in[7];
    const float* b_out = (const float*)d_in[8];
    float* out = (float*)d_out;

    _Float16* W = (_Float16*)d_ws;
    const size_t M = 16777216;
    _Float16 *q0 = W,       *v0 = W +   M, *q1 = W + 2*M,
             *v1 = W + 3*M, *q2 = W + 4*M, *v2 = W + 5*M;

    k_conv_in<<<8192, 256, 0, stream>>>(x, w_in, b_in, gma, bta, mu, var,
                                        q0, v0, q1, v1, q2, v2);
    k_attn<0><<<2048, 256, 0, stream>>>(q0, q1, v2, v2);
    k_attn<1><<<2048, 256, 0, stream>>>(q1, q2, v0, v0);
    k_attn<2><<<2048, 256, 0, stream>>>(q2, q0, v1, v1);
    k_conv_out<<<8192, 256, 0, stream>>>(v2, v0, v1, w_out, b_out, out);
}

// Round 6
// 417.566 us; speedup vs baseline: 2.7439x; 1.1763x over previous
//
#include <hip/hip_runtime.h>

// GMSA r6: conv_out restructured: 256 px/block (one (b,h) row), grid 2048,
// all-thread gather, A-frags prefetched before barrier, XCD-swizzled blocks.
// conv_in + attention unchanged from r5.
// d_ws: 6 f16 buffers of 2^24 elems: q0 v0 q1 v1 q2 v2.

typedef _Float16 f16x8 __attribute__((ext_vector_type(8)));
typedef _Float16 f16x4 __attribute__((ext_vector_type(4)));
typedef float    f32x4 __attribute__((ext_vector_type(4)));

__device__ inline f16x8 pack8(float4 a, float4 b) {
    f16x8 r;
    r[0]=(_Float16)a.x; r[1]=(_Float16)a.y; r[2]=(_Float16)a.z; r[3]=(_Float16)a.w;
    r[4]=(_Float16)b.x; r[5]=(_Float16)b.y; r[6]=(_Float16)b.z; r[7]=(_Float16)b.w;
    return r;
}

// conv_in as MFMA GEMM: D[192 o][64 px] = (W*inv)[o][96 c] x[c][px] + bias[o]
__global__ __launch_bounds__(256) void k_conv_in(
    const float* __restrict__ x, const float* __restrict__ w_in,
    const float* __restrict__ b_in, const float* __restrict__ gma,
    const float* __restrict__ bta, const float* __restrict__ mu,
    const float* __restrict__ var,
    _Float16* __restrict__ q0, _Float16* __restrict__ v0,
    _Float16* __restrict__ q1, _Float16* __restrict__ v1,
    _Float16* __restrict__ q2, _Float16* __restrict__ v2)
{
    __shared__ float xs[96*65];
    __shared__ float invs[192];
    __shared__ float bias[192];
    const int t  = threadIdx.x;
    const int wv = t >> 6, ln = t & 63;
    const int lo = ln & 15, hi = ln >> 4;

    if (t < 192) {
        float iv = gma[t] * rsqrtf(var[t] + 1e-5f);
        invs[t] = iv;
        bias[t] = b_in[t]*iv + bta[t] - mu[t]*iv;
    }

    const int pixbase = blockIdx.x * 64;
    const int b   = pixbase >> 16;
    const int rem = pixbase & 65535;
    const int hh  = rem >> 8;
    const int ww0 = rem & 255;

    {
        const float* xb = x + (size_t)b*96*65536 + rem;
        #pragma unroll
        for (int pass = 0; pass < 6; ++pass) {
            int idx = pass*256 + t;
            int c   = idx >> 4;
            int p4  = (idx & 15) << 2;
            float4 v = *reinterpret_cast<const float4*>(xb + (size_t)c*65536 + p4);
            *reinterpret_cast<float4*>(&xs[c*65 + p4]) = v;
        }
    }
    __syncthreads();

    f16x8 af[3][3];
    #pragma unroll
    for (int rf = 0; rf < 3; ++rf) {
        const int row = wv*48 + rf*16 + lo;
        const float iv = invs[row];
        #pragma unroll
        for (int ks = 0; ks < 3; ++ks) {
            const float* wp = w_in + row*96 + ks*32 + hi*8;
            float4 wa = *reinterpret_cast<const float4*>(wp);
            float4 wb = *reinterpret_cast<const float4*>(wp + 4);
            wa.x*=iv; wa.y*=iv; wa.z*=iv; wa.w*=iv;
            wb.x*=iv; wb.y*=iv; wb.z*=iv; wb.w*=iv;
            af[rf][ks] = pack8(wa, wb);
        }
    }

    f32x4 acc[3][4];
    #pragma unroll
    for (int rf = 0; rf < 3; ++rf)
        #pragma unroll
        for (int cf = 0; cf < 4; ++cf) acc[rf][cf] = f32x4{0.f,0.f,0.f,0.f};

    #pragma unroll
    for (int cf = 0; cf < 4; ++cf) {
        #pragma unroll
        for (int ks = 0; ks < 3; ++ks) {
            const float* bp = &xs[(ks*32 + hi*8)*65 + cf*16 + lo];
            f16x8 bfv;
            #pragma unroll
            for (int e = 0; e < 8; ++e) bfv[e] = (_Float16)bp[e*65];
            #pragma unroll
            for (int rf = 0; rf < 3; ++rf)
                acc[rf][cf] = __builtin_amdgcn_mfma_f32_16x16x32_f16(
                                  af[rf][ks], bfv, acc[rf][cf], 0,0,0);
        }
    }

    int ro[3][4];
    #pragma unroll
    for (int i = 0; i < 3; ++i) {
        const int lg = 2 + i;
        const int ws = 1 << lg;
        const int sft = ws >> 1;
        const int nblk = 256 >> lg;
        int h  = (hh - sft) & 255;
        int nbrow = (b*nblk + (h >> lg))*nblk;
        int hr = h & (ws-1);
        #pragma unroll
        for (int cf = 0; cf < 4; ++cf) {
            int w = (ww0 + cf*16 + lo - sft) & 255;
            ro[i][cf] = (nbrow + (w >> lg))*(ws*ws) + hr*ws + (w & (ws-1));
        }
    }

    #pragma unroll
    for (int rf = 0; rf < 3; ++rf) {
        const int base = wv*48 + rf*16;
        const int o0i  = base + hi*4;
        const int sc   = base >> 6;
        const bool isv = (base & 32) != 0;
        const int c32  = o0i & 31;
        float4 bi = *reinterpret_cast<const float4*>(&bias[o0i]);
        _Float16* tb = (sc == 0) ? (isv ? v0 : q0)
                     : (sc == 1) ? (isv ? v1 : q1)
                                 : (isv ? v2 : q2);
        #pragma unroll
        for (int cf = 0; cf < 4; ++cf) {
            f16x4 hv;
            hv[0] = (_Float16)(acc[rf][cf][0] + bi.x);
            hv[1] = (_Float16)(acc[rf][cf][1] + bi.y);
            hv[2] = (_Float16)(acc[rf][cf][2] + bi.z);
            hv[3] = (_Float16)(acc[rf][cf][3] + bi.w);
            *reinterpret_cast<f16x4*>(tb + (size_t)ro[sc][cf]*32 + c32) = hv;
        }
    }
}

// Flash attention, fp16 MFMA 16x16x32, d=32 (unchanged).
template<int GROUP>
__global__ __launch_bounds__(256) void k_attn(
    const _Float16* __restrict__ Q, const _Float16* __restrict__ Ks,
    const _Float16* Vs, _Float16* O)
{
    constexpr int S   = (GROUP==0) ? 16 : (GROUP==1) ? 64 : 256;
    constexpr int GB  = 256 / S;
    constexpr int KT  = (S < 32) ? 16 : 32;
    constexpr int NT  = S / KT;
    constexpr int CBS = KT / 16;

    __shared__ uint4    Kl[4*256];
    __shared__ _Float16 Vt[32*264 + 8];
    __shared__ _Float16 Pl[4][64*40];

    const int t = threadIdx.x;
    {
        const int g = t / S, j = t % S;
        const int bq = blockIdx.x * GB + g;
        int krow, vrow;
        if constexpr (GROUP == 0) {
            krow = (bq >> 2)*64  + (j << 2) + (bq & 3);
            vrow = (bq >> 4)*256 + (j << 4) + (bq & 15);
        } else if constexpr (GROUP == 1) {
            krow = (bq >> 2)*256 + (j << 2) + (bq & 3);
            vrow = ((bq << 2) + (j & 3))*16 + (j >> 2);
        } else {
            krow = ((bq << 4) + (j & 15))*16 + (j >> 4);
            vrow = ((bq << 2) + (j & 3))*64 + (j >> 2);
        }
        const uint4* ks = reinterpret_cast<const uint4*>(Ks + (size_t)krow*32);
        uint4 ka = ks[0], kb = ks[1], kc = ks[2], kd = ks[3];
        Kl[0*256 + t] = ka; Kl[1*256 + t] = kb;
        Kl[2*256 + t] = kc; Kl[3*256 + t] = kd;
        union { uint4 u4[4]; _Float16 h[32]; } vb;
        const uint4* vs = reinterpret_cast<const uint4*>(Vs + (size_t)vrow*32);
        vb.u4[0] = vs[0]; vb.u4[1] = vs[1]; vb.u4[2] = vs[2]; vb.u4[3] = vs[3];
        #pragma unroll
        for (int d = 0; d < 32; ++d) Vt[d*264 + t] = vb.h[d];
        Vt[(t >> 3)*264 + 256 + (t & 7)] = (_Float16)0.f;
        if (t < 8) Vt[32*264 + t] = (_Float16)0.f;
    }
    const int wv = t >> 6, ln = t & 63;
    const int lo = ln & 15, hi = ln >> 4;
    _Float16* Pw = Pl[wv];
    if constexpr (S == 16) {
        uint* pw32 = reinterpret_cast<uint*>(Pw);
        #pragma unroll
        for (int k2 = 0; k2 < 8; ++k2) {
            int idx = ln + k2*64;
            pw32[(idx >> 3)*20 + 8 + (idx & 7)] = 0u;
        }
    }
    __syncthreads();

    const int rowbase = blockIdx.x*256 + wv*64;
    f16x8 qf[4];
    #pragma unroll
    for (int rb = 0; rb < 4; ++rb) {
        uint4 qv = *reinterpret_cast<const uint4*>(
            Q + ((size_t)(rowbase + rb*16 + lo))*32 + hi*8);
        qf[rb] = __builtin_bit_cast(f16x8, qv);
    }

    f32x4 ofr[4][2];
    float m[4][4], ls[4][4];
    #pragma unroll
    for (int rb = 0; rb < 4; ++rb) {
        #pragma unroll
        for (int r = 0; r < 4; ++r) { m[rb][r] = -1e30f; ls[rb][r] = 0.f; }
        ofr[rb][0] = f32x4{0.f,0.f,0.f,0.f};
        ofr[rb][1] = f32x4{0.f,0.f,0.f,0.f};
    }
    const f32x4 zf = f32x4{0.f,0.f,0.f,0.f};

    for (int tt = 0; tt < NT; ++tt) {
        f32x4 sf[4][CBS];
        if constexpr (S == 16) {
            #pragma unroll
            for (int rb = 0; rb < 4; ++rb) {
                int key = wv*64 + rb*16 + lo;
                f16x8 bk = __builtin_bit_cast(f16x8, Kl[hi*256 + key]);
                sf[rb][0] = __builtin_amdgcn_mfma_f32_16x16x32_f16(qf[rb], bk, zf, 0,0,0);
            }
        } else {
            f16x8 bk[CBS];
            const int wb = (S == 64) ? wv*64 : 0;
            #pragma unroll
            for (int cb = 0; cb < CBS; ++cb) {
                int key = wb + tt*KT + cb*16 + lo;
                bk[cb] = __builtin_bit_cast(f16x8, Kl[hi*256 + key]);
            }
            #pragma unroll
            for (int rb = 0; rb < 4; ++rb)
                #pragma unroll
                for (int cb = 0; cb < CBS; ++cb)
                    sf[rb][cb] = __builtin_amdgcn_mfma_f32_16x16x32_f16(qf[rb], bk[cb], zf, 0,0,0);
        }

        #pragma unroll
        for (int rb = 0; rb < 4; ++rb) {
            #pragma unroll
            for (int r = 0; r < 4; ++r) {
                float tm = sf[rb][0][r];
                #pragma unroll
                for (int cb = 1; cb < CBS; ++cb) tm = fmaxf(tm, sf[rb][cb][r]);
                tm = fmaxf(tm, __shfl_xor(tm, 1));
                tm = fmaxf(tm, __shfl_xor(tm, 2));
                tm = fmaxf(tm, __shfl_xor(tm, 4));
                tm = fmaxf(tm, __shfl_xor(tm, 8));
                float mn = fmaxf(m[rb][r], tm);
                float sc = __expf(m[rb][r] - mn);
                m[rb][r] = mn;
                ls[rb][r] *= sc;
                ofr[rb][0][r] *= sc;
                ofr[rb][1][r] *= sc;
                #pragma unroll
                for (int cb = 0; cb < CBS; ++cb) {
                    float p = __expf(sf[rb][cb][r] - mn);
                    ls[rb][r] += p;
                    Pw[(rb*16 + hi*4 + r)*40 + cb*16 + lo] = (_Float16)p;
                }
            }
        }

        #pragma unroll
        for (int rb = 0; rb < 4; ++rb) {
            f16x8 pa = *reinterpret_cast<const f16x8*>(Pw + (rb*16 + lo)*40 + hi*8);
            const int wb = (S == 16) ? wv*64 + rb*16 : (S == 64) ? wv*64 : 0;
            const int key0 = wb + tt*KT + hi*8;
            #pragma unroll
            for (int dcb = 0; dcb < 2; ++dcb) {
                f16x8 bv = *reinterpret_cast<const f16x8*>(Vt + (dcb*16 + lo)*264 + key0);
                ofr[rb][dcb] = __builtin_amdgcn_mfma_f32_16x16x32_f16(pa, bv, ofr[rb][dcb], 0,0,0);
            }
        }
    }

    #pragma unroll
    for (int rb = 0; rb < 4; ++rb) {
        #pragma unroll
        for (int r = 0; r < 4; ++r) {
            float v = ls[rb][r];
            v += __shfl_xor(v, 1);
            v += __shfl_xor(v, 2);
            v += __shfl_xor(v, 4);
            v += __shfl_xor(v, 8);
            ls[rb][r] = 1.f / v;
        }
        #pragma unroll
        for (int dcb = 0; dcb < 2; ++dcb)
            #pragma unroll
            for (int r = 0; r < 4; ++r) {
                float ov = ofr[rb][dcb][r] * ls[rb][r];
                int row = rowbase + rb*16 + hi*4 + r;
                O[(size_t)row*32 + dcb*16 + lo] = (_Float16)ov;
            }
    }
}

// conv_out v2: block = one (b,h) row, 256 px. D[96 o][256 px] = w_out y + b.
__global__ __launch_bounds__(256) void k_conv_out(
    const _Float16* __restrict__ o0, const _Float16* __restrict__ o1,
    const _Float16* __restrict__ o2, const float* __restrict__ w_out,
    const float* __restrict__ b_out, float* __restrict__ out)
{
    constexpr int YS = 104;                 // f16 row stride (208 B, 16B-aligned)
    __shared__ _Float16 yt[256*YS];         // [px][c]
    const int t  = threadIdx.x;
    const int wv = t >> 6, ln = t & 63;
    const int lo = ln & 15, hi = ln >> 4;
    const int bid = (int)blockIdx.x;
    const int swz = (bid & 7)*256 + (bid >> 3);   // XCD-contiguous (b,h) slabs
    const int b = swz >> 8;
    const int h = swz & 255;

    // gather all 3 scales for px = t (unwindow + roll folded into addressing)
    #pragma unroll
    for (int i = 0; i < 3; ++i) {
        const int lg = 2 + i;
        const int ws = 1 << lg;
        const int sft = ws >> 1;
        const int nblk = 256 >> lg;
        int hh = (h - sft) & 255;
        int w  = (t - sft) & 255;
        int nb = (b*nblk + (hh >> lg))*nblk + (w >> lg);
        int roff = nb*(ws*ws) + (hh & (ws-1))*ws + (w & (ws-1));
        const uint4* src = reinterpret_cast<const uint4*>(
            (i==0 ? o0 : i==1 ? o1 : o2) + (size_t)roff*32);
        uint4 r0 = src[0], r1 = src[1], r2 = src[2], r3 = src[3];
        uint4* dst = reinterpret_cast<uint4*>(&yt[t*YS + i*32]);
        dst[0] = r0; dst[1] = r1; dst[2] = r2; dst[3] = r3;
    }

    // A-frags from w_out (L2-resident) — issued before the barrier to overlap
    f16x8 af[6][3];
    #pragma unroll
    for (int rf = 0; rf < 6; ++rf)
        #pragma unroll
        for (int ks = 0; ks < 3; ++ks) {
            const float* wp = w_out + (rf*16 + lo)*96 + ks*32 + hi*8;
            float4 wa = *reinterpret_cast<const float4*>(wp);
            float4 wb = *reinterpret_cast<const float4*>(wp + 4);
            af[rf][ks] = pack8(wa, wb);
        }
    __syncthreads();

    f32x4 acc[6][4];
    #pragma unroll
    for (int rf = 0; rf < 6; ++rf)
        #pragma unroll
        for (int cf = 0; cf < 4; ++cf) acc[rf][cf] = f32x4{0.f,0.f,0.f,0.f};

    #pragma unroll
    for (int cf = 0; cf < 4; ++cf) {
        const int px = wv*64 + cf*16 + lo;
        #pragma unroll
        for (int ks = 0; ks < 3; ++ks) {
            f16x8 bfv = *reinterpret_cast<const f16x8*>(&yt[px*YS + ks*32 + hi*8]);
            #pragma unroll
            for (int rf = 0; rf < 6; ++rf)
                acc[rf][cf] = __builtin_amdgcn_mfma_f32_16x16x32_f16(
                                  af[rf][ks], bfv, acc[rf][cf], 0,0,0);
        }
    }

    const size_t obase = (size_t)b*96*65536 + (size_t)h*256;
    #pragma unroll
    for (int rf = 0; rf < 6; ++rf) {
        const int oo = rf*16 + hi*4;
        float4 bi = *reinterpret_cast<const float4*>(b_out + oo);
        #pragma unroll
        for (int cf = 0; cf < 4; ++cf) {
            const int px = wv*64 + cf*16 + lo;
            out[obase + (size_t)(oo+0)*65536 + px] = acc[rf][cf][0] + bi.x;
            out[obase + (size_t)(oo+1)*65536 + px] = acc[rf][cf][1] + bi.y;
            out[obase + (size_t)(oo+2)*65536 + px] = acc[rf][cf][2] + bi.z;
            out[obase + (size_t)(oo+3)*65536 + px] = acc[rf][cf][3] + bi.w;
        }
    }
}

extern "C" void kernel_launch(void* const* d_in, const int* in_sizes, int n_in,
                              void* d_out, int out_size, void* d_ws, size_t ws_size,
                              hipStream_t stream)
{
    const float* x     = (const float*)d_in[0];
    const float* w_in  = (const float*)d_in[1];
    const float* b_in  = (const float*)d_in[2];
    const float* gma   = (const float*)d_in[3];
    const float* bta   = (const float*)d_in[4];
    const float* mu    = (const float*)d_in[5];
    const float* var   = (const float*)d_in[6];
    const float* w_out = (const float*)d_in[7];
    const float* b_out = (const float*)d_in[8];
    float* out = (float*)d_out;

    _Float16* W = (_Float16*)d_ws;
    const size_t M = 16777216;
    _Float16 *q0 = W,       *v0 = W +   M, *q1 = W + 2*M,
             *v1 = W + 3*M, *q2 = W + 4*M, *v2 = W + 5*M;

    k_conv_in<<<8192, 256, 0, stream>>>(x, w_in, b_in, gma, bta, mu, var,
                                        q0, v0, q1, v1, q2, v2);
    k_attn<0><<<2048, 256, 0, stream>>>(q0, q1, v2, v2);
    k_attn<1><<<2048, 256, 0, stream>>>(q1, q2, v0, v0);
    k_attn<2><<<2048, 256, 0, stream>>>(q2, q0, v1, v1);
    k_conv_out<<<2048, 256, 0, stream>>>(v2, v0, v1, w_out, b_out, out);
}

// Round 7
// 333.560 us; speedup vs baseline: 3.4349x; 1.2518x over previous
//
#include <hip/hip_runtime.h>

// GMSA r7: conv_in -> f16 [px][104] staging + b128 frags (conflict-free);
// attn -> swapped QK^T (q in lo-lane: 2-shfl row max) + exp2-domain softmax
// (sqrt(log2e) folded into q-buffer scale in conv_in). conv_out as r6.
// d_ws: 6 f16 buffers of 2^24 elems: q0 v0 q1 v1 q2 v2.

typedef _Float16 f16x8 __attribute__((ext_vector_type(8)));
typedef _Float16 f16x4 __attribute__((ext_vector_type(4)));
typedef _Float16 f16x2 __attribute__((ext_vector_type(2)));
typedef float    f32x4 __attribute__((ext_vector_type(4)));

__device__ inline f16x8 pack8(float4 a, float4 b) {
    f16x8 r;
    r[0]=(_Float16)a.x; r[1]=(_Float16)a.y; r[2]=(_Float16)a.z; r[3]=(_Float16)a.w;
    r[4]=(_Float16)b.x; r[5]=(_Float16)b.y; r[6]=(_Float16)b.z; r[7]=(_Float16)b.w;
    return r;
}
__device__ inline float exp2_fast(float x) {    // v_exp_f32: D = 2^S0
    float r; asm("v_exp_f32 %0, %1" : "=v"(r) : "v"(x)); return r;
}

// conv_in MFMA GEMM: block = 128 px, D[192 o][128 px] = (W*inv)[o][96] x[96][px] + bias.
// x staged f16 [px][104]; q-half outputs scaled by sqrt(log2e) (exp2 softmax).
__global__ __launch_bounds__(256) void k_conv_in(
    const float* __restrict__ x, const float* __restrict__ w_in,
    const float* __restrict__ b_in, const float* __restrict__ gma,
    const float* __restrict__ bta, const float* __restrict__ mu,
    const float* __restrict__ var,
    _Float16* __restrict__ q0, _Float16* __restrict__ v0,
    _Float16* __restrict__ q1, _Float16* __restrict__ v1,
    _Float16* __restrict__ q2, _Float16* __restrict__ v2)
{
    __shared__ _Float16 yt[128*104];   // [px][c], 208B stride: conflict-free b128
    __shared__ float invs[192];
    __shared__ float bias[192];
    const int t  = threadIdx.x;
    const int wv = t >> 6, ln = t & 63;
    const int lo = ln & 15, hi = ln >> 4;

    if (t < 192) {
        const float qs = ((t & 63) < 32) ? 1.2011224087864498f : 1.0f; // sqrt(log2e)
        float iv = gma[t] * rsqrtf(var[t] + 1e-5f);
        invs[t] = iv * qs;
        bias[t] = (b_in[t]*iv + bta[t] - mu[t]*iv) * qs;
    }
    __syncthreads();

    const int pixbase = blockIdx.x * 128;
    const int b   = pixbase >> 16;
    const int rem = pixbase & 65535;
    const int hh  = rem >> 8;
    const int ww0 = rem & 255;

    {   // stage: thread owns px = t&127, 6 channel-octets (coalesced scalar loads)
        const int px   = t & 127;
        const int oct0 = t >> 7;
        const float* xb = x + (size_t)b*96*65536 + rem + px;
        #pragma unroll
        for (int j = 0; j < 6; ++j) {
            const int c0 = (oct0 + 2*j) * 8;
            const float* xp = xb + (size_t)c0*65536;
            f16x8 hv;
            #pragma unroll
            for (int e = 0; e < 8; ++e) hv[e] = (_Float16)xp[(size_t)e*65536];
            *reinterpret_cast<f16x8*>(&yt[px*104 + c0]) = hv;
        }
    }

    // A-frags (W*inv), all in regs; issued while staging drains
    const int row_base = (wv >> 1) * 96;
    const int px_base  = (wv & 1) * 64;
    f16x8 af[6][3];
    #pragma unroll
    for (int rf = 0; rf < 6; ++rf) {
        const int row = row_base + rf*16 + lo;
        const float iv = invs[row];
        #pragma unroll
        for (int ks = 0; ks < 3; ++ks) {
            const float* wp = w_in + row*96 + ks*32 + hi*8;
            float4 wa = *reinterpret_cast<const float4*>(wp);
            float4 wb = *reinterpret_cast<const float4*>(wp + 4);
            wa.x*=iv; wa.y*=iv; wa.z*=iv; wa.w*=iv;
            wb.x*=iv; wb.y*=iv; wb.z*=iv; wb.w*=iv;
            af[rf][ks] = pack8(wa, wb);
        }
    }
    __syncthreads();

    f32x4 acc[6][4];
    #pragma unroll
    for (int rf = 0; rf < 6; ++rf)
        #pragma unroll
        for (int cf = 0; cf < 4; ++cf) acc[rf][cf] = f32x4{0.f,0.f,0.f,0.f};

    #pragma unroll
    for (int cf = 0; cf < 4; ++cf) {
        const int px = px_base + cf*16 + lo;
        #pragma unroll
        for (int ks = 0; ks < 3; ++ks) {
            f16x8 bfv = *reinterpret_cast<const f16x8*>(&yt[px*104 + ks*32 + hi*8]);
            #pragma unroll
            for (int rf = 0; rf < 6; ++rf)
                acc[rf][cf] = __builtin_amdgcn_mfma_f32_16x16x32_f16(
                                  af[rf][ks], bfv, acc[rf][cf], 0,0,0);
        }
    }

    int ro[3][4];
    #pragma unroll
    for (int i = 0; i < 3; ++i) {
        const int lg = 2 + i;
        const int ws = 1 << lg;
        const int sft = ws >> 1;
        const int nblk = 256 >> lg;
        int h  = (hh - sft) & 255;
        int nbrow = (b*nblk + (h >> lg))*nblk;
        int hr = h & (ws-1);
        #pragma unroll
        for (int cf = 0; cf < 4; ++cf) {
            int w = (ww0 + px_base + cf*16 + lo - sft) & 255;
            ro[i][cf] = (nbrow + (w >> lg))*(ws*ws) + hr*ws + (w & (ws-1));
        }
    }

    #pragma unroll
    for (int rf = 0; rf < 6; ++rf) {
        const int base = row_base + rf*16;
        const int o0i  = base + hi*4;
        const int sc   = base >> 6;
        const bool isv = (base & 32) != 0;
        const int c32  = o0i & 31;
        float4 bi = *reinterpret_cast<const float4*>(&bias[o0i]);
        _Float16* tb = (sc == 0) ? (isv ? v0 : q0)
                     : (sc == 1) ? (isv ? v1 : q1)
                                 : (isv ? v2 : q2);
        #pragma unroll
        for (int cf = 0; cf < 4; ++cf) {
            f16x4 hv;
            hv[0] = (_Float16)(acc[rf][cf][0] + bi.x);
            hv[1] = (_Float16)(acc[rf][cf][1] + bi.y);
            hv[2] = (_Float16)(acc[rf][cf][2] + bi.z);
            hv[3] = (_Float16)(acc[rf][cf][3] + bi.w);
            *reinterpret_cast<f16x4*>(tb + (size_t)ro[sc][cf]*32 + c32) = hv;
        }
    }
}

// Flash attention, swapped QK^T (C[key][q]: q = lo lane), exp2-domain softmax.
// GROUP 0: nb=32768,S=16  Q=q0 K=q1 V=v2 | GROUP 1: nb=8192,S=64 Q=q1 K=q2 V=v0
// GROUP 2: nb=2048, S=256 Q=q2 K=q0 V=v1
template<int GROUP>
__global__ __launch_bounds__(256) void k_attn(
    const _Float16* __restrict__ Q, const _Float16* __restrict__ Ks,
    const _Float16* Vs, _Float16* O)
{
    constexpr int S   = (GROUP==0) ? 16 : (GROUP==1) ? 64 : 256;
    constexpr int GB  = 256 / S;
    constexpr int KT  = (S < 32) ? 16 : 32;
    constexpr int NT  = S / KT;
    constexpr int CBS = KT / 16;

    __shared__ uint4    Kl[4*256];
    __shared__ _Float16 Vt[32*264 + 8];
    __shared__ _Float16 Pl[4][64*40];

    const int t = threadIdx.x;
    {
        const int g = t / S, j = t % S;
        const int bq = blockIdx.x * GB + g;
        int krow, vrow;
        if constexpr (GROUP == 0) {
            krow = (bq >> 2)*64  + (j << 2) + (bq & 3);
            vrow = (bq >> 4)*256 + (j << 4) + (bq & 15);
        } else if constexpr (GROUP == 1) {
            krow = (bq >> 2)*256 + (j << 2) + (bq & 3);
            vrow = ((bq << 2) + (j & 3))*16 + (j >> 2);
        } else {
            krow = ((bq << 4) + (j & 15))*16 + (j >> 4);
            vrow = ((bq << 2) + (j & 3))*64 + (j >> 2);
        }
        const uint4* ks = reinterpret_cast<const uint4*>(Ks + (size_t)krow*32);
        uint4 ka = ks[0], kb = ks[1], kc = ks[2], kd = ks[3];
        Kl[0*256 + t] = ka; Kl[1*256 + t] = kb;
        Kl[2*256 + t] = kc; Kl[3*256 + t] = kd;
        union { uint4 u4[4]; _Float16 h[32]; } vb;
        const uint4* vs = reinterpret_cast<const uint4*>(Vs + (size_t)vrow*32);
        vb.u4[0] = vs[0]; vb.u4[1] = vs[1]; vb.u4[2] = vs[2]; vb.u4[3] = vs[3];
        #pragma unroll
        for (int d = 0; d < 32; ++d) Vt[d*264 + t] = vb.h[d];
        Vt[(t >> 3)*264 + 256 + (t & 7)] = (_Float16)0.f;
        if (t < 8) Vt[32*264 + t] = (_Float16)0.f;
    }
    const int wv = t >> 6, ln = t & 63;
    const int lo = ln & 15, hi = ln >> 4;
    _Float16* Pw = Pl[wv];
    if constexpr (S == 16) {    // zero pad-cols 16..31 once (stay zero)
        uint* pw32 = reinterpret_cast<uint*>(Pw);
        #pragma unroll
        for (int k2 = 0; k2 < 8; ++k2) {
            int idx = ln + k2*64;
            pw32[(idx >> 3)*20 + 8 + (idx & 7)] = 0u;
        }
    }
    __syncthreads();

    const int rowbase = blockIdx.x*256 + wv*64;
    f16x8 qf[4];
    #pragma unroll
    for (int rb = 0; rb < 4; ++rb) {
        uint4 qv = *reinterpret_cast<const uint4*>(
            Q + ((size_t)(rowbase + rb*16 + lo))*32 + hi*8);
        qf[rb] = __builtin_bit_cast(f16x8, qv);
    }

    f32x4 ofr[4][2];
    float m[4], ls[4];
    #pragma unroll
    for (int rb = 0; rb < 4; ++rb) {
        m[rb] = -1e30f; ls[rb] = 0.f;
        ofr[rb][0] = f32x4{0.f,0.f,0.f,0.f};
        ofr[rb][1] = f32x4{0.f,0.f,0.f,0.f};
    }
    const f32x4 zf = f32x4{0.f,0.f,0.f,0.f};

    for (int tt = 0; tt < NT; ++tt) {
        // swapped: sf[rb][cb] = K x Q  ->  C[row=key(hi*4+r)][col=q(lo)]
        f32x4 sf[4][CBS];
        if constexpr (S == 16) {
            #pragma unroll
            for (int rb = 0; rb < 4; ++rb) {
                int key = wv*64 + rb*16 + lo;
                f16x8 bk = __builtin_bit_cast(f16x8, Kl[hi*256 + key]);
                sf[rb][0] = __builtin_amdgcn_mfma_f32_16x16x32_f16(bk, qf[rb], zf, 0,0,0);
            }
        } else {
            f16x8 bk[CBS];
            const int wb = (S == 64) ? wv*64 : 0;
            #pragma unroll
            for (int cb = 0; cb < CBS; ++cb) {
                int key = wb + tt*KT + cb*16 + lo;
                bk[cb] = __builtin_bit_cast(f16x8, Kl[hi*256 + key]);
            }
            #pragma unroll
            for (int rb = 0; rb < 4; ++rb)
                #pragma unroll
                for (int cb = 0; cb < CBS; ++cb)
                    sf[rb][cb] = __builtin_amdgcn_mfma_f32_16x16x32_f16(bk[cb], qf[rb], zf, 0,0,0);
        }

        #pragma unroll
        for (int rb = 0; rb < 4; ++rb) {
            float tm = sf[rb][0][0];
            #pragma unroll
            for (int cb = 0; cb < CBS; ++cb)
                #pragma unroll
                for (int r = 0; r < 4; ++r)
                    if (cb | r) tm = fmaxf(tm, sf[rb][cb][r]);
            tm = fmaxf(tm, __shfl_xor(tm, 16));
            tm = fmaxf(tm, __shfl_xor(tm, 32));
            float mn = fmaxf(m[rb], tm);
            float sc = exp2_fast(m[rb] - mn);
            m[rb] = mn;
            float ps = 0.f;
            #pragma unroll
            for (int cb = 0; cb < CBS; ++cb) {
                float p0 = exp2_fast(sf[rb][cb][0] - mn);
                float p1 = exp2_fast(sf[rb][cb][1] - mn);
                float p2 = exp2_fast(sf[rb][cb][2] - mn);
                float p3 = exp2_fast(sf[rb][cb][3] - mn);
                ps += (p0+p1)+(p2+p3);
                f16x2 w01; w01[0] = (_Float16)p0; w01[1] = (_Float16)p1;
                f16x2 w23; w23[0] = (_Float16)p2; w23[1] = (_Float16)p3;
                _Float16* pp = Pw + (rb*16 + lo)*40 + cb*16 + hi*4;
                *reinterpret_cast<f16x2*>(pp)     = w01;
                *reinterpret_cast<f16x2*>(pp + 2) = w23;
            }
            ls[rb] = ls[rb]*sc + ps;
            // transpose sc to O-domain rows q' = hi*4+r
            float s0 = __shfl(sc, hi*4 + 0);
            float s1 = __shfl(sc, hi*4 + 1);
            float s2 = __shfl(sc, hi*4 + 2);
            float s3 = __shfl(sc, hi*4 + 3);
            ofr[rb][0][0]*=s0; ofr[rb][0][1]*=s1; ofr[rb][0][2]*=s2; ofr[rb][0][3]*=s3;
            ofr[rb][1][0]*=s0; ofr[rb][1][1]*=s1; ofr[rb][1][2]*=s2; ofr[rb][1][3]*=s3;
        }

        #pragma unroll
        for (int rb = 0; rb < 4; ++rb) {
            f16x8 pa = *reinterpret_cast<const f16x8*>(Pw + (rb*16 + lo)*40 + hi*8);
            const int wb = (S == 16) ? wv*64 + rb*16 : (S == 64) ? wv*64 : 0;
            const int key0 = wb + tt*KT + hi*8;
            #pragma unroll
            for (int dcb = 0; dcb < 2; ++dcb) {
                f16x8 bv = *reinterpret_cast<const f16x8*>(Vt + (dcb*16 + lo)*264 + key0);
                ofr[rb][dcb] = __builtin_amdgcn_mfma_f32_16x16x32_f16(pa, bv, ofr[rb][dcb], 0,0,0);
            }
        }
    }

    #pragma unroll
    for (int rb = 0; rb < 4; ++rb) {
        float v = ls[rb];
        v += __shfl_xor(v, 16);
        v += __shfl_xor(v, 32);
        float linv = 1.f / v;
        float l0 = __shfl(linv, hi*4 + 0);
        float l1 = __shfl(linv, hi*4 + 1);
        float l2 = __shfl(linv, hi*4 + 2);
        float l3 = __shfl(linv, hi*4 + 3);
        #pragma unroll
        for (int dcb = 0; dcb < 2; ++dcb) {
            float lr[4] = {l0, l1, l2, l3};
            #pragma unroll
            for (int r = 0; r < 4; ++r) {
                float ov = ofr[rb][dcb][r] * lr[r];
                int row = rowbase + rb*16 + hi*4 + r;
                O[(size_t)row*32 + dcb*16 + lo] = (_Float16)ov;
            }
        }
    }
}

// conv_out: block = one (b,h) row, 256 px (unchanged from r6).
__global__ __launch_bounds__(256) void k_conv_out(
    const _Float16* __restrict__ o0, const _Float16* __restrict__ o1,
    const _Float16* __restrict__ o2, const float* __restrict__ w_out,
    const float* __restrict__ b_out, float* __restrict__ out)
{
    constexpr int YS = 104;
    __shared__ _Float16 yt[256*YS];
    const int t  = threadIdx.x;
    const int wv = t >> 6, ln = t & 63;
    const int lo = ln & 15, hi = ln >> 4;
    const int bid = (int)blockIdx.x;
    const int swz = (bid & 7)*256 + (bid >> 3);
    const int b = swz >> 8;
    const int h = swz & 255;

    #pragma unroll
    for (int i = 0; i < 3; ++i) {
        const int lg = 2 + i;
        const int ws = 1 << lg;
        const int sft = ws >> 1;
        const int nblk = 256 >> lg;
        int hh = (h - sft) & 255;
        int w  = (t - sft) & 255;
        int nb = (b*nblk + (hh >> lg))*nblk + (w >> lg);
        int roff = nb*(ws*ws) + (hh & (ws-1))*ws + (w & (ws-1));
        const uint4* src = reinterpret_cast<const uint4*>(
            (i==0 ? o0 : i==1 ? o1 : o2) + (size_t)roff*32);
        uint4 r0 = src[0], r1 = src[1], r2 = src[2], r3 = src[3];
        uint4* dst = reinterpret_cast<uint4*>(&yt[t*YS + i*32]);
        dst[0] = r0; dst[1] = r1; dst[2] = r2; dst[3] = r3;
    }

    f16x8 af[6][3];
    #pragma unroll
    for (int rf = 0; rf < 6; ++rf)
        #pragma unroll
        for (int ks = 0; ks < 3; ++ks) {
            const float* wp = w_out + (rf*16 + lo)*96 + ks*32 + hi*8;
            float4 wa = *reinterpret_cast<const float4*>(wp);
            float4 wb = *reinterpret_cast<const float4*>(wp + 4);
            af[rf][ks] = pack8(wa, wb);
        }
    __syncthreads();

    f32x4 acc[6][4];
    #pragma unroll
    for (int rf = 0; rf < 6; ++rf)
        #pragma unroll
        for (int cf = 0; cf < 4; ++cf) acc[rf][cf] = f32x4{0.f,0.f,0.f,0.f};

    #pragma unroll
    for (int cf = 0; cf < 4; ++cf) {
        const int px = wv*64 + cf*16 + lo;
        #pragma unroll
        for (int ks = 0; ks < 3; ++ks) {
            f16x8 bfv = *reinterpret_cast<const f16x8*>(&yt[px*YS + ks*32 + hi*8]);
            #pragma unroll
            for (int rf = 0; rf < 6; ++rf)
                acc[rf][cf] = __builtin_amdgcn_mfma_f32_16x16x32_f16(
                                  af[rf][ks], bfv, acc[rf][cf], 0,0,0);
        }
    }

    const size_t obase = (size_t)b*96*65536 + (size_t)h*256;
    #pragma unroll
    for (int rf = 0; rf < 6; ++rf) {
        const int oo = rf*16 + hi*4;
        float4 bi = *reinterpret_cast<const float4*>(b_out + oo);
        #pragma unroll
        for (int cf = 0; cf < 4; ++cf) {
            const int px = wv*64 + cf*16 + lo;
            out[obase + (size_t)(oo+0)*65536 + px] = acc[rf][cf][0] + bi.x;
            out[obase + (size_t)(oo+1)*65536 + px] = acc[rf][cf][1] + bi.y;
            out[obase + (size_t)(oo+2)*65536 + px] = acc[rf][cf][2] + bi.z;
            out[obase + (size_t)(oo+3)*65536 + px] = acc[rf][cf][3] + bi.w;
        }
    }
}

extern "C" void kernel_launch(void* const* d_in, const int* in_sizes, int n_in,
                              void* d_out, int out_size, void* d_ws, size_t ws_size,
                              hipStream_t stream)
{
    const float* x     = (const float*)d_in[0];
    const float* w_in  = (const float*)d_in[1];
    const float* b_in  = (const float*)d_in[2];
    const float* gma   = (const float*)d_in[3];
    const float* bta   = (const float*)d_in[4];
    const float* mu    = (const float*)d_in[5];
    const float* var   = (const float*)d_in[6];
    const float* w_out = (const float*)d_in[7];
    const float* b_out = (const float*)d_in[8];
    float* out = (float*)d_out;

    _Float16* W = (_Float16*)d_ws;
    const size_t M = 16777216;
    _Float16 *q0 = W,       *v0 = W +   M, *q1 = W + 2*M,
             *v1 = W + 3*M, *q2 = W + 4*M, *v2 = W + 5*M;

    k_conv_in<<<4096, 256, 0, stream>>>(x, w_in, b_in, gma, bta, mu, var,
                                        q0, v0, q1, v1, q2, v2);
    k_attn<0><<<2048, 256, 0, stream>>>(q0, q1, v2, v2);
    k_attn<1><<<2048, 256, 0, stream>>>(q1, q2, v0, v0);
    k_attn<2><<<2048, 256, 0, stream>>>(q2, q0, v1, v1);
    k_conv_out<<<2048, 256, 0, stream>>>(v2, v0, v1, w_out, b_out, out);
}

// Round 8
// 287.748 us; speedup vs baseline: 3.9818x; 1.1592x over previous
//
#include <hip/hip_runtime.h>

// GMSA r8: k_prep folds w_in*inv*qs -> f16 wf, bias f32, w_out -> f16 wo (once).
// conv_in: 128-px blocks, K in 3x32-chunks, f32 [32][132] LDS, reg double-buffer
// (T14 issue-early/write-late) -> HBM-bound. attn unchanged. conv_out: f16 wo frags.
// d_ws: 6 f16 buffers of 2^24 + wf(18432 f16) + bias(192 f32) + wo(9216 f16).

typedef _Float16 f16x8 __attribute__((ext_vector_type(8)));
typedef _Float16 f16x4 __attribute__((ext_vector_type(4)));
typedef _Float16 f16x2 __attribute__((ext_vector_type(2)));
typedef float    f32x4 __attribute__((ext_vector_type(4)));

__device__ inline float exp2_fast(float x) {    // v_exp_f32: D = 2^S0
    float r; asm("v_exp_f32 %0, %1" : "=v"(r) : "v"(x)); return r;
}

// ---- one-shot weight prep -------------------------------------------------
__global__ __launch_bounds__(256) void k_prep(
    const float* __restrict__ w_in, const float* __restrict__ b_in,
    const float* __restrict__ gma, const float* __restrict__ bta,
    const float* __restrict__ mu,  const float* __restrict__ var,
    const float* __restrict__ w_out,
    _Float16* __restrict__ wf, float* __restrict__ bs, _Float16* __restrict__ wo)
{
    const int t = threadIdx.x;
    if (t < 192) {
        const float qs = ((t & 63) < 32) ? 1.2011224087864498f : 1.0f; // sqrt(log2e)
        float iv = gma[t] * rsqrtf(var[t] + 1e-5f);
        float s  = iv * qs;
        bs[t] = (b_in[t]*iv + bta[t] - mu[t]*iv) * qs;
        #pragma unroll
        for (int c4 = 0; c4 < 96; c4 += 4) {
            float4 w = *reinterpret_cast<const float4*>(w_in + t*96 + c4);
            f16x4 h;
            h[0]=(_Float16)(w.x*s); h[1]=(_Float16)(w.y*s);
            h[2]=(_Float16)(w.z*s); h[3]=(_Float16)(w.w*s);
            *reinterpret_cast<f16x4*>(wf + t*96 + c4) = h;
        }
    }
    if (t < 96) {
        #pragma unroll
        for (int c4 = 0; c4 < 96; c4 += 4) {
            float4 w = *reinterpret_cast<const float4*>(w_out + t*96 + c4);
            f16x4 h;
            h[0]=(_Float16)w.x; h[1]=(_Float16)w.y;
            h[2]=(_Float16)w.z; h[3]=(_Float16)w.w;
            *reinterpret_cast<f16x4*>(wo + t*96 + c4) = h;
        }
    }
}

// ---- conv_in: D[192 o][128 px] = wf[o][96] x[96][px] + bs[o], windowed scatter
__global__ __launch_bounds__(256) void k_conv_in(
    const float* __restrict__ x, const _Float16* __restrict__ wf,
    const float* __restrict__ bs,
    _Float16* __restrict__ q0, _Float16* __restrict__ v0,
    _Float16* __restrict__ q1, _Float16* __restrict__ v1,
    _Float16* __restrict__ q2, _Float16* __restrict__ v2)
{
    __shared__ float xs[32*132];        // chunk of 32 channels x 128 px (+pad)
    const int t  = threadIdx.x;
    const int wv = t >> 6, ln = t & 63;
    const int lo = ln & 15, hi = ln >> 4;
    const int oh = wv >> 1, ph = wv & 1;      // wave = 96 o x 64 px

    const int pixbase = blockIdx.x * 128;
    const int b   = pixbase >> 16;
    const int rem = pixbase & 65535;
    const int hh  = rem >> 8;
    const int ww0 = rem & 255;

    const int r0 = t >> 5;                    // 0..7
    const int q4 = (t & 31) * 4;              // px-quad within row
    const float* xb = x + (size_t)b*96*65536 + rem + q4;

    float4 RA0, RA1, RA2, RA3, RB0, RB1, RB2, RB3;

#define STAGE_LOAD(Ra,Rb,Rc,Rd,c0) { \
    Ra = *reinterpret_cast<const float4*>(xb + (size_t)(c0 + r0     )*65536); \
    Rb = *reinterpret_cast<const float4*>(xb + (size_t)(c0 + r0 +  8)*65536); \
    Rc = *reinterpret_cast<const float4*>(xb + (size_t)(c0 + r0 + 16)*65536); \
    Rd = *reinterpret_cast<const float4*>(xb + (size_t)(c0 + r0 + 24)*65536); }
#define STAGE_WRITE(Ra,Rb,Rc,Rd) { \
    *reinterpret_cast<float4*>(&xs[(r0     )*132 + q4]) = Ra; \
    *reinterpret_cast<float4*>(&xs[(r0 +  8)*132 + q4]) = Rb; \
    *reinterpret_cast<float4*>(&xs[(r0 + 16)*132 + q4]) = Rc; \
    *reinterpret_cast<float4*>(&xs[(r0 + 24)*132 + q4]) = Rd; }

    STAGE_LOAD(RA0, RA1, RA2, RA3, 0);

    // A-frags: rows oh*96 + rf*16 + lo, k = ks*32 + hi*8 (pre-folded f16)
    f16x8 af[6][3];
    const _Float16* wrow0 = wf + (size_t)(oh*96 + lo)*96 + hi*8;
    #pragma unroll
    for (int rf = 0; rf < 6; ++rf)
        #pragma unroll
        for (int ks = 0; ks < 3; ++ks)
            af[rf][ks] = *reinterpret_cast<const f16x8*>(wrow0 + rf*16*96 + ks*32);

    f32x4 acc[6][4];
    #pragma unroll
    for (int rf = 0; rf < 6; ++rf)
        #pragma unroll
        for (int cf = 0; cf < 4; ++cf) acc[rf][cf] = f32x4{0.f,0.f,0.f,0.f};

#define COMPUTE(j) { \
    _Pragma("unroll") for (int cf = 0; cf < 4; ++cf) { \
        const float* bp = &xs[hi*8*132 + ph*64 + cf*16 + lo]; \
        f16x8 bfv; \
        _Pragma("unroll") for (int e = 0; e < 8; ++e) bfv[e] = (_Float16)bp[e*132]; \
        _Pragma("unroll") for (int rf = 0; rf < 6; ++rf) \
            acc[rf][cf] = __builtin_amdgcn_mfma_f32_16x16x32_f16( \
                              af[rf][j], bfv, acc[rf][cf], 0,0,0); } }

    STAGE_WRITE(RA0, RA1, RA2, RA3);
    STAGE_LOAD(RB0, RB1, RB2, RB3, 32);    // in flight during COMPUTE(0)
    __syncthreads();
    COMPUTE(0);
    __syncthreads();
    STAGE_WRITE(RB0, RB1, RB2, RB3);
    STAGE_LOAD(RA0, RA1, RA2, RA3, 64);    // in flight during COMPUTE(1)
    __syncthreads();
    COMPUTE(1);
    __syncthreads();
    STAGE_WRITE(RA0, RA1, RA2, RA3);
    __syncthreads();
    COMPUTE(2);

    // windowed scatter (roll folded), px = ph*64 + cf*16 + lo
    int ro[3][4];
    #pragma unroll
    for (int i = 0; i < 3; ++i) {
        const int lg = 2 + i;
        const int ws = 1 << lg;
        const int sft = ws >> 1;
        const int nblk = 256 >> lg;
        int h  = (hh - sft) & 255;
        int nbrow = (b*nblk + (h >> lg))*nblk;
        int hr = h & (ws-1);
        #pragma unroll
        for (int cf = 0; cf < 4; ++cf) {
            int w = (ww0 + ph*64 + cf*16 + lo - sft) & 255;
            ro[i][cf] = (nbrow + (w >> lg))*(ws*ws) + hr*ws + (w & (ws-1));
        }
    }
    #pragma unroll
    for (int rf = 0; rf < 6; ++rf) {
        const int base = oh*96 + rf*16;
        const int o0i  = base + hi*4;
        const int sc   = base >> 6;
        const bool isv = (base & 32) != 0;
        const int c32  = o0i & 31;
        float4 bi = *reinterpret_cast<const float4*>(bs + o0i);
        _Float16* tb = (sc == 0) ? (isv ? v0 : q0)
                     : (sc == 1) ? (isv ? v1 : q1)
                                 : (isv ? v2 : q2);
        #pragma unroll
        for (int cf = 0; cf < 4; ++cf) {
            f16x4 hv;
            hv[0] = (_Float16)(acc[rf][cf][0] + bi.x);
            hv[1] = (_Float16)(acc[rf][cf][1] + bi.y);
            hv[2] = (_Float16)(acc[rf][cf][2] + bi.z);
            hv[3] = (_Float16)(acc[rf][cf][3] + bi.w);
            *reinterpret_cast<f16x4*>(tb + (size_t)ro[sc][cf]*32 + c32) = hv;
        }
    }
#undef STAGE_LOAD
#undef STAGE_WRITE
#undef COMPUTE
}

// ---- Flash attention, swapped QK^T + exp2 softmax (unchanged from r7) -----
template<int GROUP>
__global__ __launch_bounds__(256) void k_attn(
    const _Float16* __restrict__ Q, const _Float16* __restrict__ Ks,
    const _Float16* Vs, _Float16* O)
{
    constexpr int S   = (GROUP==0) ? 16 : (GROUP==1) ? 64 : 256;
    constexpr int GB  = 256 / S;
    constexpr int KT  = (S < 32) ? 16 : 32;
    constexpr int NT  = S / KT;
    constexpr int CBS = KT / 16;

    __shared__ uint4    Kl[4*256];
    __shared__ _Float16 Vt[32*264 + 8];
    __shared__ _Float16 Pl[4][64*40];

    const int t = threadIdx.x;
    {
        const int g = t / S, j = t % S;
        const int bq = blockIdx.x * GB + g;
        int krow, vrow;
        if constexpr (GROUP == 0) {
            krow = (bq >> 2)*64  + (j << 2) + (bq & 3);
            vrow = (bq >> 4)*256 + (j << 4) + (bq & 15);
        } else if constexpr (GROUP == 1) {
            krow = (bq >> 2)*256 + (j << 2) + (bq & 3);
            vrow = ((bq << 2) + (j & 3))*16 + (j >> 2);
        } else {
            krow = ((bq << 4) + (j & 15))*16 + (j >> 4);
            vrow = ((bq << 2) + (j & 3))*64 + (j >> 2);
        }
        const uint4* ks = reinterpret_cast<const uint4*>(Ks + (size_t)krow*32);
        uint4 ka = ks[0], kb = ks[1], kc = ks[2], kd = ks[3];
        Kl[0*256 + t] = ka; Kl[1*256 + t] = kb;
        Kl[2*256 + t] = kc; Kl[3*256 + t] = kd;
        union { uint4 u4[4]; _Float16 h[32]; } vb;
        const uint4* vs = reinterpret_cast<const uint4*>(Vs + (size_t)vrow*32);
        vb.u4[0] = vs[0]; vb.u4[1] = vs[1]; vb.u4[2] = vs[2]; vb.u4[3] = vs[3];
        #pragma unroll
        for (int d = 0; d < 32; ++d) Vt[d*264 + t] = vb.h[d];
        Vt[(t >> 3)*264 + 256 + (t & 7)] = (_Float16)0.f;
        if (t < 8) Vt[32*264 + t] = (_Float16)0.f;
    }
    const int wv = t >> 6, ln = t & 63;
    const int lo = ln & 15, hi = ln >> 4;
    _Float16* Pw = Pl[wv];
    if constexpr (S == 16) {
        uint* pw32 = reinterpret_cast<uint*>(Pw);
        #pragma unroll
        for (int k2 = 0; k2 < 8; ++k2) {
            int idx = ln + k2*64;
            pw32[(idx >> 3)*20 + 8 + (idx & 7)] = 0u;
        }
    }
    __syncthreads();

    const int rowbase = blockIdx.x*256 + wv*64;
    f16x8 qf[4];
    #pragma unroll
    for (int rb = 0; rb < 4; ++rb) {
        uint4 qv = *reinterpret_cast<const uint4*>(
            Q + ((size_t)(rowbase + rb*16 + lo))*32 + hi*8);
        qf[rb] = __builtin_bit_cast(f16x8, qv);
    }

    f32x4 ofr[4][2];
    float m[4], ls[4];
    #pragma unroll
    for (int rb = 0; rb < 4; ++rb) {
        m[rb] = -1e30f; ls[rb] = 0.f;
        ofr[rb][0] = f32x4{0.f,0.f,0.f,0.f};
        ofr[rb][1] = f32x4{0.f,0.f,0.f,0.f};
    }
    const f32x4 zf = f32x4{0.f,0.f,0.f,0.f};

    for (int tt = 0; tt < NT; ++tt) {
        f32x4 sf[4][CBS];
        if constexpr (S == 16) {
            #pragma unroll
            for (int rb = 0; rb < 4; ++rb) {
                int key = wv*64 + rb*16 + lo;
                f16x8 bk = __builtin_bit_cast(f16x8, Kl[hi*256 + key]);
                sf[rb][0] = __builtin_amdgcn_mfma_f32_16x16x32_f16(bk, qf[rb], zf, 0,0,0);
            }
        } else {
            f16x8 bk[CBS];
            const int wb = (S == 64) ? wv*64 : 0;
            #pragma unroll
            for (int cb = 0; cb < CBS; ++cb) {
                int key = wb + tt*KT + cb*16 + lo;
                bk[cb] = __builtin_bit_cast(f16x8, Kl[hi*256 + key]);
            }
            #pragma unroll
            for (int rb = 0; rb < 4; ++rb)
                #pragma unroll
                for (int cb = 0; cb < CBS; ++cb)
                    sf[rb][cb] = __builtin_amdgcn_mfma_f32_16x16x32_f16(bk[cb], qf[rb], zf, 0,0,0);
        }

        #pragma unroll
        for (int rb = 0; rb < 4; ++rb) {
            float tm = sf[rb][0][0];
            #pragma unroll
            for (int cb = 0; cb < CBS; ++cb)
                #pragma unroll
                for (int r = 0; r < 4; ++r)
                    if (cb | r) tm = fmaxf(tm, sf[rb][cb][r]);
            tm = fmaxf(tm, __shfl_xor(tm, 16));
            tm = fmaxf(tm, __shfl_xor(tm, 32));
            float mn = fmaxf(m[rb], tm);
            float sc = exp2_fast(m[rb] - mn);
            m[rb] = mn;
            float ps = 0.f;
            #pragma unroll
            for (int cb = 0; cb < CBS; ++cb) {
                float p0 = exp2_fast(sf[rb][cb][0] - mn);
                float p1 = exp2_fast(sf[rb][cb][1] - mn);
                float p2 = exp2_fast(sf[rb][cb][2] - mn);
                float p3 = exp2_fast(sf[rb][cb][3] - mn);
                ps += (p0+p1)+(p2+p3);
                f16x2 w01; w01[0] = (_Float16)p0; w01[1] = (_Float16)p1;
                f16x2 w23; w23[0] = (_Float16)p2; w23[1] = (_Float16)p3;
                _Float16* pp = Pw + (rb*16 + lo)*40 + cb*16 + hi*4;
                *reinterpret_cast<f16x2*>(pp)     = w01;
                *reinterpret_cast<f16x2*>(pp + 2) = w23;
            }
            ls[rb] = ls[rb]*sc + ps;
            float s0 = __shfl(sc, hi*4 + 0);
            float s1 = __shfl(sc, hi*4 + 1);
            float s2 = __shfl(sc, hi*4 + 2);
            float s3 = __shfl(sc, hi*4 + 3);
            ofr[rb][0][0]*=s0; ofr[rb][0][1]*=s1; ofr[rb][0][2]*=s2; ofr[rb][0][3]*=s3;
            ofr[rb][1][0]*=s0; ofr[rb][1][1]*=s1; ofr[rb][1][2]*=s2; ofr[rb][1][3]*=s3;
        }

        #pragma unroll
        for (int rb = 0; rb < 4; ++rb) {
            f16x8 pa = *reinterpret_cast<const f16x8*>(Pw + (rb*16 + lo)*40 + hi*8);
            const int wb = (S == 16) ? wv*64 + rb*16 : (S == 64) ? wv*64 : 0;
            const int key0 = wb + tt*KT + hi*8;
            #pragma unroll
            for (int dcb = 0; dcb < 2; ++dcb) {
                f16x8 bv = *reinterpret_cast<const f16x8*>(Vt + (dcb*16 + lo)*264 + key0);
                ofr[rb][dcb] = __builtin_amdgcn_mfma_f32_16x16x32_f16(pa, bv, ofr[rb][dcb], 0,0,0);
            }
        }
    }

    #pragma unroll
    for (int rb = 0; rb < 4; ++rb) {
        float v = ls[rb];
        v += __shfl_xor(v, 16);
        v += __shfl_xor(v, 32);
        float linv = 1.f / v;
        float l0 = __shfl(linv, hi*4 + 0);
        float l1 = __shfl(linv, hi*4 + 1);
        float l2 = __shfl(linv, hi*4 + 2);
        float l3 = __shfl(linv, hi*4 + 3);
        #pragma unroll
        for (int dcb = 0; dcb < 2; ++dcb) {
            float lr[4] = {l0, l1, l2, l3};
            #pragma unroll
            for (int r = 0; r < 4; ++r) {
                float ov = ofr[rb][dcb][r] * lr[r];
                int row = rowbase + rb*16 + hi*4 + r;
                O[(size_t)row*32 + dcb*16 + lo] = (_Float16)ov;
            }
        }
    }
}

// ---- conv_out (r6 structure; A-frags from pre-folded f16 wo) --------------
__global__ __launch_bounds__(256) void k_conv_out(
    const _Float16* __restrict__ o0, const _Float16* __restrict__ o1,
    const _Float16* __restrict__ o2, const _Float16* __restrict__ wo,
    const float* __restrict__ b_out, float* __restrict__ out)
{
    constexpr int YS = 104;
    __shared__ _Float16 yt[256*YS];
    const int t  = threadIdx.x;
    const int wv = t >> 6, ln = t & 63;
    const int lo = ln & 15, hi = ln >> 4;
    const int bid = (int)blockIdx.x;
    const int swz = (bid & 7)*256 + (bid >> 3);
    const int b = swz >> 8;
    const int h = swz & 255;

    #pragma unroll
    for (int i = 0; i < 3; ++i) {
        const int lg = 2 + i;
        const int ws = 1 << lg;
        const int sft = ws >> 1;
        const int nblk = 256 >> lg;
        int hh = (h - sft) & 255;
        int w  = (t - sft) & 255;
        int nb = (b*nblk + (hh >> lg))*nblk + (w >> lg);
        int roff = nb*(ws*ws) + (hh & (ws-1))*ws + (w & (ws-1));
        const uint4* src = reinterpret_cast<const uint4*>(
            (i==0 ? o0 : i==1 ? o1 : o2) + (size_t)roff*32);
        uint4 r0 = src[0], r1 = src[1], r2 = src[2], r3 = src[3];
        uint4* dst = reinterpret_cast<uint4*>(&yt[t*YS + i*32]);
        dst[0] = r0; dst[1] = r1; dst[2] = r2; dst[3] = r3;
    }

    f16x8 af[6][3];
    #pragma unroll
    for (int rf = 0; rf < 6; ++rf)
        #pragma unroll
        for (int ks = 0; ks < 3; ++ks)
            af[rf][ks] = *reinterpret_cast<const f16x8*>(
                wo + (rf*16 + lo)*96 + ks*32 + hi*8);
    __syncthreads();

    f32x4 acc[6][4];
    #pragma unroll
    for (int rf = 0; rf < 6; ++rf)
        #pragma unroll
        for (int cf = 0; cf < 4; ++cf) acc[rf][cf] = f32x4{0.f,0.f,0.f,0.f};

    #pragma unroll
    for (int cf = 0; cf < 4; ++cf) {
        const int px = wv*64 + cf*16 + lo;
        #pragma unroll
        for (int ks = 0; ks < 3; ++ks) {
            f16x8 bfv = *reinterpret_cast<const f16x8*>(&yt[px*YS + ks*32 + hi*8]);
            #pragma unroll
            for (int rf = 0; rf < 6; ++rf)
                acc[rf][cf] = __builtin_amdgcn_mfma_f32_16x16x32_f16(
                                  af[rf][ks], bfv, acc[rf][cf], 0,0,0);
        }
    }

    const size_t obase = (size_t)b*96*65536 + (size_t)h*256;
    #pragma unroll
    for (int rf = 0; rf < 6; ++rf) {
        const int oo = rf*16 + hi*4;
        float4 bi = *reinterpret_cast<const float4*>(b_out + oo);
        #pragma unroll
        for (int cf = 0; cf < 4; ++cf) {
            const int px = wv*64 + cf*16 + lo;
            out[obase + (size_t)(oo+0)*65536 + px] = acc[rf][cf][0] + bi.x;
            out[obase + (size_t)(oo+1)*65536 + px] = acc[rf][cf][1] + bi.y;
            out[obase + (size_t)(oo+2)*65536 + px] = acc[rf][cf][2] + bi.z;
            out[obase + (size_t)(oo+3)*65536 + px] = acc[rf][cf][3] + bi.w;
        }
    }
}

extern "C" void kernel_launch(void* const* d_in, const int* in_sizes, int n_in,
                              void* d_out, int out_size, void* d_ws, size_t ws_size,
                              hipStream_t stream)
{
    const float* x     = (const float*)d_in[0];
    const float* w_in  = (const float*)d_in[1];
    const float* b_in  = (const float*)d_in[2];
    const float* gma   = (const float*)d_in[3];
    const float* bta   = (const float*)d_in[4];
    const float* mu    = (const float*)d_in[5];
    const float* var   = (const float*)d_in[6];
    const float* w_out = (const float*)d_in[7];
    const float* b_out = (const float*)d_in[8];
    float* out = (float*)d_out;

    _Float16* W = (_Float16*)d_ws;
    const size_t M = 16777216;
    _Float16 *q0 = W,       *v0 = W +   M, *q1 = W + 2*M,
             *v1 = W + 3*M, *q2 = W + 4*M, *v2 = W + 5*M;
    _Float16* wf = W + 6*M;                          // 192*96 f16
    float*    bs = (float*)(W + 6*M + 18432);        // 192 f32
    _Float16* wo = W + 6*M + 18432 + 384;            // 96*96 f16

    k_prep<<<1, 256, 0, stream>>>(w_in, b_in, gma, bta, mu, var, w_out, wf, bs, wo);
    k_conv_in<<<4096, 256, 0, stream>>>(x, wf, bs, q0, v0, q1, v1, q2, v2);
    k_attn<0><<<2048, 256, 0, stream>>>(q0, q1, v2, v2);
    k_attn<1><<<2048, 256, 0, stream>>>(q1, q2, v0, v0);
    k_attn<2><<<2048, 256, 0, stream>>>(q2, q0, v1, v1);
    k_conv_out<<<2048, 256, 0, stream>>>(v2, v0, v1, wo, b_out, out);
}

// Round 10
// 276.849 us; speedup vs baseline: 4.1385x; 1.0394x over previous
//
#include <hip/hip_runtime.h>

// GMSA r10 (= r9 + compile fix): conv_in stages channel-paired f16 dwords
// (cvt_pkrtz) -> B-frag = 4 ds_read_b32 + bit_cast, ping-pong LDS. The 3
// independent attentions merged into ONE kernel (grid 6144, shared LDS arena).
// d_ws: 6 f16 buffers of 2^24 + wf + bias + wo (prep kernel).

typedef _Float16 f16x8 __attribute__((ext_vector_type(8)));
typedef _Float16 f16x4 __attribute__((ext_vector_type(4)));
typedef _Float16 f16x2 __attribute__((ext_vector_type(2)));
typedef float    f32x4 __attribute__((ext_vector_type(4)));

__device__ inline float exp2_fast(float x) {
    float r; asm("v_exp_f32 %0, %1" : "=v"(r) : "v"(x)); return r;
}
__device__ inline unsigned pkrtz(float a, float b) {
    return __builtin_bit_cast(unsigned, __builtin_amdgcn_cvt_pkrtz(a, b));
}

// ---- one-shot weight prep -------------------------------------------------
__global__ __launch_bounds__(256) void k_prep(
    const float* __restrict__ w_in, const float* __restrict__ b_in,
    const float* __restrict__ gma, const float* __restrict__ bta,
    const float* __restrict__ mu,  const float* __restrict__ var,
    const float* __restrict__ w_out,
    _Float16* __restrict__ wf, float* __restrict__ bs, _Float16* __restrict__ wo)
{
    const int t = threadIdx.x;
    if (t < 192) {
        const float qs = ((t & 63) < 32) ? 1.2011224087864498f : 1.0f; // sqrt(log2e)
        float iv = gma[t] * rsqrtf(var[t] + 1e-5f);
        float s  = iv * qs;
        bs[t] = (b_in[t]*iv + bta[t] - mu[t]*iv) * qs;
        #pragma unroll
        for (int c4 = 0; c4 < 96; c4 += 4) {
            float4 w = *reinterpret_cast<const float4*>(w_in + t*96 + c4);
            f16x4 h;
            h[0]=(_Float16)(w.x*s); h[1]=(_Float16)(w.y*s);
            h[2]=(_Float16)(w.z*s); h[3]=(_Float16)(w.w*s);
            *reinterpret_cast<f16x4*>(wf + t*96 + c4) = h;
        }
    }
    if (t < 96) {
        #pragma unroll
        for (int c4 = 0; c4 < 96; c4 += 4) {
            float4 w = *reinterpret_cast<const float4*>(w_out + t*96 + c4);
            f16x4 h;
            h[0]=(_Float16)w.x; h[1]=(_Float16)w.y;
            h[2]=(_Float16)w.z; h[3]=(_Float16)w.w;
            *reinterpret_cast<f16x4*>(wo + t*96 + c4) = h;
        }
    }
}

// ---- conv_in: D[192 o][128 px] = wf[o][96] x[96][px] + bs[o] --------------
__global__ __launch_bounds__(256) void k_conv_in(
    const float* __restrict__ x, const _Float16* __restrict__ wf,
    const float* __restrict__ bs,
    _Float16* __restrict__ q0, _Float16* __restrict__ v0,
    _Float16* __restrict__ q1, _Float16* __restrict__ v1,
    _Float16* __restrict__ q2, _Float16* __restrict__ v2)
{
    __shared__ unsigned xs2[2][16*132];   // dword = f16 pair (2c2, 2c2+1) per px
    const int t  = threadIdx.x;
    const int wv = t >> 6, ln = t & 63;
    const int lo = ln & 15, hi = ln >> 4;
    const int oh = wv >> 1, ph = wv & 1;      // wave = 96 o x 64 px

    const int pixbase = blockIdx.x * 128;
    const int b   = pixbase >> 16;
    const int rem = pixbase & 65535;
    const int hh  = rem >> 8;
    const int ww0 = rem & 255;

    const int r0 = t >> 5;                    // pair-row 0..7 (and +8)
    const int q4 = (t & 31) << 2;
    const float* xb = x + (size_t)b*96*65536 + rem + q4;

    float4 L0, L1, L2, L3;

#define CLOAD(c0) { \
    L0 = *reinterpret_cast<const float4*>(xb + (size_t)(c0 + 2*r0     )*65536); \
    L1 = *reinterpret_cast<const float4*>(xb + (size_t)(c0 + 2*r0 +  1)*65536); \
    L2 = *reinterpret_cast<const float4*>(xb + (size_t)(c0 + 2*r0 + 16)*65536); \
    L3 = *reinterpret_cast<const float4*>(xb + (size_t)(c0 + 2*r0 + 17)*65536); }
#define CWRITE(bf) { \
    uint4 u0, u1; \
    u0.x = pkrtz(L0.x, L1.x); u0.y = pkrtz(L0.y, L1.y); \
    u0.z = pkrtz(L0.z, L1.z); u0.w = pkrtz(L0.w, L1.w); \
    u1.x = pkrtz(L2.x, L3.x); u1.y = pkrtz(L2.y, L3.y); \
    u1.z = pkrtz(L2.z, L3.z); u1.w = pkrtz(L2.w, L3.w); \
    *reinterpret_cast<uint4*>(&xs2[bf][ r0     *132 + q4]) = u0; \
    *reinterpret_cast<uint4*>(&xs2[bf][(r0 + 8)*132 + q4]) = u1; }
#define CCOMP(bf, ks) { \
    _Pragma("unroll") for (int cf = 0; cf < 4; ++cf) { \
        const unsigned* bp = &xs2[bf][hi*4*132 + ph*64 + cf*16 + lo]; \
        uint4 u; u.x = bp[0]; u.y = bp[132]; u.z = bp[264]; u.w = bp[396]; \
        f16x8 bfv = __builtin_bit_cast(f16x8, u); \
        _Pragma("unroll") for (int rf = 0; rf < 6; ++rf) \
            acc[rf][cf] = __builtin_amdgcn_mfma_f32_16x16x32_f16( \
                              af[rf][ks], bfv, acc[rf][cf], 0,0,0); } }

    CLOAD(0);

    f16x8 af[6][3];
    const _Float16* wrow0 = wf + (size_t)(oh*96 + lo)*96 + hi*8;
    #pragma unroll
    for (int rf = 0; rf < 6; ++rf)
        #pragma unroll
        for (int ks = 0; ks < 3; ++ks)
            af[rf][ks] = *reinterpret_cast<const f16x8*>(wrow0 + rf*16*96 + ks*32);

    f32x4 acc[6][4];
    #pragma unroll
    for (int rf = 0; rf < 6; ++rf)
        #pragma unroll
        for (int cf = 0; cf < 4; ++cf) acc[rf][cf] = f32x4{0.f,0.f,0.f,0.f};

    CWRITE(0);
    __syncthreads();
    CLOAD(32);                 // chunk1 in flight under COMPUTE(0)
    CCOMP(0, 0);
    CWRITE(1);
    __syncthreads();
    CLOAD(64);                 // chunk2 in flight under COMPUTE(1)
    CCOMP(1, 1);
    CWRITE(0);                 // safe: all waves left chunk0 at last barrier
    __syncthreads();
    CCOMP(0, 2);

    // windowed scatter (roll folded), px = ph*64 + cf*16 + lo
    int ro[3][4];
    #pragma unroll
    for (int i = 0; i < 3; ++i) {
        const int lg = 2 + i;
        const int ws = 1 << lg;
        const int sft = ws >> 1;
        const int nblk = 256 >> lg;
        int h  = (hh - sft) & 255;
        int nbrow = (b*nblk + (h >> lg))*nblk;
        int hr = h & (ws-1);
        #pragma unroll
        for (int cf = 0; cf < 4; ++cf) {
            int w = (ww0 + ph*64 + cf*16 + lo - sft) & 255;
            ro[i][cf] = (nbrow + (w >> lg))*(ws*ws) + hr*ws + (w & (ws-1));
        }
    }
    #pragma unroll
    for (int rf = 0; rf < 6; ++rf) {
        const int base = oh*96 + rf*16;
        const int o0i  = base + hi*4;
        const int sc   = base >> 6;
        const bool isv = (base & 32) != 0;
        const int c32  = o0i & 31;
        float4 bi = *reinterpret_cast<const float4*>(bs + o0i);
        _Float16* tb = (sc == 0) ? (isv ? v0 : q0)
                     : (sc == 1) ? (isv ? v1 : q1)
                                 : (isv ? v2 : q2);
        #pragma unroll
        for (int cf = 0; cf < 4; ++cf) {
            f16x4 hv;
            hv[0] = (_Float16)(acc[rf][cf][0] + bi.x);
            hv[1] = (_Float16)(acc[rf][cf][1] + bi.y);
            hv[2] = (_Float16)(acc[rf][cf][2] + bi.z);
            hv[3] = (_Float16)(acc[rf][cf][3] + bi.w);
            *reinterpret_cast<f16x4*>(tb + (size_t)ro[sc][cf]*32 + c32) = hv;
        }
    }
#undef CLOAD
#undef CWRITE
#undef CCOMP
}

// ---- Flash attention body (swapped QK^T + exp2), LDS passed in ------------
template<int GROUP>
__device__ __forceinline__ void attn_body(
    int bid, uint4* Kl, _Float16* Vt, _Float16* Pl,
    const _Float16* __restrict__ Q, const _Float16* __restrict__ Ks,
    const _Float16* Vs, _Float16* O)
{
    constexpr int S   = (GROUP==0) ? 16 : (GROUP==1) ? 64 : 256;
    constexpr int GB  = 256 / S;
    constexpr int KT  = (S < 32) ? 16 : 32;
    constexpr int NT  = S / KT;
    constexpr int CBS = KT / 16;

    const int t = threadIdx.x;
    {
        const int g = t / S, j = t % S;
        const int bq = bid * GB + g;
        int krow, vrow;
        if constexpr (GROUP == 0) {
            krow = (bq >> 2)*64  + (j << 2) + (bq & 3);
            vrow = (bq >> 4)*256 + (j << 4) + (bq & 15);
        } else if constexpr (GROUP == 1) {
            krow = (bq >> 2)*256 + (j << 2) + (bq & 3);
            vrow = ((bq << 2) + (j & 3))*16 + (j >> 2);
        } else {
            krow = ((bq << 4) + (j & 15))*16 + (j >> 4);
            vrow = ((bq << 2) + (j & 3))*64 + (j >> 2);
        }
        const uint4* ks = reinterpret_cast<const uint4*>(Ks + (size_t)krow*32);
        uint4 ka = ks[0], kb = ks[1], kc = ks[2], kd = ks[3];
        Kl[0*256 + t] = ka; Kl[1*256 + t] = kb;
        Kl[2*256 + t] = kc; Kl[3*256 + t] = kd;
        union { uint4 u4[4]; _Float16 h[32]; } vb;
        const uint4* vs = reinterpret_cast<const uint4*>(Vs + (size_t)vrow*32);
        vb.u4[0] = vs[0]; vb.u4[1] = vs[1]; vb.u4[2] = vs[2]; vb.u4[3] = vs[3];
        #pragma unroll
        for (int d = 0; d < 32; ++d) Vt[d*264 + t] = vb.h[d];
        Vt[(t >> 3)*264 + 256 + (t & 7)] = (_Float16)0.f;
        if (t < 8) Vt[32*264 + t] = (_Float16)0.f;
    }
    const int wv = t >> 6, ln = t & 63;
    const int lo = ln & 15, hi = ln >> 4;
    _Float16* Pw = Pl + wv*(64*40);
    if constexpr (S == 16) {
        uint* pw32 = reinterpret_cast<uint*>(Pw);
        #pragma unroll
        for (int k2 = 0; k2 < 8; ++k2) {
            int idx = ln + k2*64;
            pw32[(idx >> 3)*20 + 8 + (idx & 7)] = 0u;
        }
    }
    __syncthreads();

    const int rowbase = bid*256 + wv*64;
    f16x8 qf[4];
    #pragma unroll
    for (int rb = 0; rb < 4; ++rb) {
        uint4 qv = *reinterpret_cast<const uint4*>(
            Q + ((size_t)(rowbase + rb*16 + lo))*32 + hi*8);
        qf[rb] = __builtin_bit_cast(f16x8, qv);
    }

    f32x4 ofr[4][2];
    float m[4], ls[4];
    #pragma unroll
    for (int rb = 0; rb < 4; ++rb) {
        m[rb] = -1e30f; ls[rb] = 0.f;
        ofr[rb][0] = f32x4{0.f,0.f,0.f,0.f};
        ofr[rb][1] = f32x4{0.f,0.f,0.f,0.f};
    }
    const f32x4 zf = f32x4{0.f,0.f,0.f,0.f};

    for (int tt = 0; tt < NT; ++tt) {
        f32x4 sf[4][CBS];
        if constexpr (S == 16) {
            #pragma unroll
            for (int rb = 0; rb < 4; ++rb) {
                int key = wv*64 + rb*16 + lo;
                f16x8 bk = __builtin_bit_cast(f16x8, Kl[hi*256 + key]);
                sf[rb][0] = __builtin_amdgcn_mfma_f32_16x16x32_f16(bk, qf[rb], zf, 0,0,0);
            }
        } else {
            f16x8 bk[CBS];
            const int wb = (S == 64) ? wv*64 : 0;
            #pragma unroll
            for (int cb = 0; cb < CBS; ++cb) {
                int key = wb + tt*KT + cb*16 + lo;
                bk[cb] = __builtin_bit_cast(f16x8, Kl[hi*256 + key]);
            }
            #pragma unroll
            for (int rb = 0; rb < 4; ++rb)
                #pragma unroll
                for (int cb = 0; cb < CBS; ++cb)
                    sf[rb][cb] = __builtin_amdgcn_mfma_f32_16x16x32_f16(bk[cb], qf[rb], zf, 0,0,0);
        }

        #pragma unroll
        for (int rb = 0; rb < 4; ++rb) {
            float tm = sf[rb][0][0];
            #pragma unroll
            for (int cb = 0; cb < CBS; ++cb)
                #pragma unroll
                for (int r = 0; r < 4; ++r)
                    if (cb | r) tm = fmaxf(tm, sf[rb][cb][r]);
            tm = fmaxf(tm, __shfl_xor(tm, 16));
            tm = fmaxf(tm, __shfl_xor(tm, 32));
            float mn = fmaxf(m[rb], tm);
            float sc = exp2_fast(m[rb] - mn);
            m[rb] = mn;
            float ps = 0.f;
            #pragma unroll
            for (int cb = 0; cb < CBS; ++cb) {
                float p0 = exp2_fast(sf[rb][cb][0] - mn);
                float p1 = exp2_fast(sf[rb][cb][1] - mn);
                float p2 = exp2_fast(sf[rb][cb][2] - mn);
                float p3 = exp2_fast(sf[rb][cb][3] - mn);
                ps += (p0+p1)+(p2+p3);
                unsigned w01 = pkrtz(p0, p1);
                unsigned w23 = pkrtz(p2, p3);
                _Float16* pp = Pw + (rb*16 + lo)*40 + cb*16 + hi*4;
                *reinterpret_cast<unsigned*>(pp)     = w01;
                *reinterpret_cast<unsigned*>(pp + 2) = w23;
            }
            ls[rb] = ls[rb]*sc + ps;
            float s0 = __shfl(sc, hi*4 + 0);
            float s1 = __shfl(sc, hi*4 + 1);
            float s2 = __shfl(sc, hi*4 + 2);
            float s3 = __shfl(sc, hi*4 + 3);
            ofr[rb][0][0]*=s0; ofr[rb][0][1]*=s1; ofr[rb][0][2]*=s2; ofr[rb][0][3]*=s3;
            ofr[rb][1][0]*=s0; ofr[rb][1][1]*=s1; ofr[rb][1][2]*=s2; ofr[rb][1][3]*=s3;
        }

        #pragma unroll
        for (int rb = 0; rb < 4; ++rb) {
            f16x8 pa = *reinterpret_cast<const f16x8*>(Pw + (rb*16 + lo)*40 + hi*8);
            const int wb = (S == 16) ? wv*64 + rb*16 : (S == 64) ? wv*64 : 0;
            const int key0 = wb + tt*KT + hi*8;
            #pragma unroll
            for (int dcb = 0; dcb < 2; ++dcb) {
                f16x8 bv = *reinterpret_cast<const f16x8*>(Vt + (dcb*16 + lo)*264 + key0);
                ofr[rb][dcb] = __builtin_amdgcn_mfma_f32_16x16x32_f16(pa, bv, ofr[rb][dcb], 0,0,0);
            }
        }
    }

    #pragma unroll
    for (int rb = 0; rb < 4; ++rb) {
        float v = ls[rb];
        v += __shfl_xor(v, 16);
        v += __shfl_xor(v, 32);
        float linv = 1.f / v;
        float l0 = __shfl(linv, hi*4 + 0);
        float l1 = __shfl(linv, hi*4 + 1);
        float l2 = __shfl(linv, hi*4 + 2);
        float l3 = __shfl(linv, hi*4 + 3);
        #pragma unroll
        for (int dcb = 0; dcb < 2; ++dcb) {
            float lr[4] = {l0, l1, l2, l3};
            #pragma unroll
            for (int r = 0; r < 4; ++r) {
                float ov = ofr[rb][dcb][r] * lr[r];
                int row = rowbase + rb*16 + hi*4 + r;
                O[(size_t)row*32 + dcb*16 + lo] = (_Float16)ov;
            }
        }
    }
}

// one kernel, 3 groups: bid<2048 -> G0, <4096 -> G1, else G2 (independent)
__global__ __launch_bounds__(256) void k_attn_all(
    const _Float16* __restrict__ q0, const _Float16* __restrict__ v0,
    const _Float16* __restrict__ q1, const _Float16* __restrict__ v1,
    const _Float16* __restrict__ q2, const _Float16* __restrict__ v2)
{
    __shared__ __align__(16) char smem[16384 + 16912 + 20480];
    uint4*    Kl = reinterpret_cast<uint4*>(smem);
    _Float16* Vt = reinterpret_cast<_Float16*>(smem + 16384);
    _Float16* Pl = reinterpret_cast<_Float16*>(smem + 16384 + 16912);
    const int bid = (int)blockIdx.x;
    if (bid < 2048)
        attn_body<0>(bid, Kl, Vt, Pl, q0, q1, v2, const_cast<_Float16*>(v2));
    else if (bid < 4096)
        attn_body<1>(bid - 2048, Kl, Vt, Pl, q1, q2, v0, const_cast<_Float16*>(v0));
    else
        attn_body<2>(bid - 4096, Kl, Vt, Pl, q2, q0, v1, const_cast<_Float16*>(v1));
}

// ---- conv_out (r6 structure; A-frags from pre-folded f16 wo) --------------
__global__ __launch_bounds__(256) void k_conv_out(
    const _Float16* __restrict__ o0, const _Float16* __restrict__ o1,
    const _Float16* __restrict__ o2, const _Float16* __restrict__ wo,
    const float* __restrict__ b_out, float* __restrict__ out)
{
    constexpr int YS = 104;
    __shared__ _Float16 yt[256*YS];
    const int t  = threadIdx.x;
    const int wv = t >> 6, ln = t & 63;
    const int lo = ln & 15, hi = ln >> 4;
    const int bid = (int)blockIdx.x;
    const int swz = (bid & 7)*256 + (bid >> 3);
    const int b = swz >> 8;
    const int h = swz & 255;

    #pragma unroll
    for (int i = 0; i < 3; ++i) {
        const int lg = 2 + i;
        const int ws = 1 << lg;
        const int sft = ws >> 1;
        const int nblk = 256 >> lg;
        int hh = (h - sft) & 255;
        int w  = (t - sft) & 255;
        int nb = (b*nblk + (hh >> lg))*nblk + (w >> lg);
        int roff = nb*(ws*ws) + (hh & (ws-1))*ws + (w & (ws-1));
        const uint4* src = reinterpret_cast<const uint4*>(
            (i==0 ? o0 : i==1 ? o1 : o2) + (size_t)roff*32);
        uint4 r0 = src[0], r1 = src[1], r2 = src[2], r3 = src[3];
        uint4* dst = reinterpret_cast<uint4*>(&yt[t*YS + i*32]);
        dst[0] = r0; dst[1] = r1; dst[2] = r2; dst[3] = r3;
    }

    f16x8 af[6][3];
    #pragma unroll
    for (int rf = 0; rf < 6; ++rf)
        #pragma unroll
        for (int ks = 0; ks < 3; ++ks)
            af[rf][ks] = *reinterpret_cast<const f16x8*>(
                wo + (rf*16 + lo)*96 + ks*32 + hi*8);
    __syncthreads();

    f32x4 acc[6][4];
    #pragma unroll
    for (int rf = 0; rf < 6; ++rf)
        #pragma unroll
        for (int cf = 0; cf < 4; ++cf) acc[rf][cf] = f32x4{0.f,0.f,0.f,0.f};

    #pragma unroll
    for (int cf = 0; cf < 4; ++cf) {
        const int px = wv*64 + cf*16 + lo;
        #pragma unroll
        for (int ks = 0; ks < 3; ++ks) {
            f16x8 bfv = *reinterpret_cast<const f16x8*>(&yt[px*YS + ks*32 + hi*8]);
            #pragma unroll
            for (int rf = 0; rf < 6; ++rf)
                acc[rf][cf] = __builtin_amdgcn_mfma_f32_16x16x32_f16(
                                  af[rf][ks], bfv, acc[rf][cf], 0,0,0);
        }
    }

    const size_t obase = (size_t)b*96*65536 + (size_t)h*256;
    #pragma unroll
    for (int rf = 0; rf < 6; ++rf) {
        const int oo = rf*16 + hi*4;
        float4 bi = *reinterpret_cast<const float4*>(b_out + oo);
        #pragma unroll
        for (int cf = 0; cf < 4; ++cf) {
            const int px = wv*64 + cf*16 + lo;
            out[obase + (size_t)(oo+0)*65536 + px] = acc[rf][cf][0] + bi.x;
            out[obase + (size_t)(oo+1)*65536 + px] = acc[rf][cf][1] + bi.y;
            out[obase + (size_t)(oo+2)*65536 + px] = acc[rf][cf][2] + bi.z;
            out[obase + (size_t)(oo+3)*65536 + px] = acc[rf][cf][3] + bi.w;
        }
    }
}

extern "C" void kernel_launch(void* const* d_in, const int* in_sizes, int n_in,
                              void* d_out, int out_size, void* d_ws, size_t ws_size,
                              hipStream_t stream)
{
    const float* x     = (const float*)d_in[0];
    const float* w_in  = (const float*)d_in[1];
    const float* b_in  = (const float*)d_in[2];
    const float* gma   = (const float*)d_in[3];
    const float* bta   = (const float*)d_in[4];
    const float* mu    = (const float*)d_in[5];
    const float* var   = (const float*)d_in[6];
    const float* w_out = (const float*)d_in[7];
    const float* b_out = (const float*)d_in[8];
    float* out = (float*)d_out;

    _Float16* W = (_Float16*)d_ws;
    const size_t M = 16777216;
    _Float16 *q0 = W,       *v0 = W +   M, *q1 = W + 2*M,
             *v1 = W + 3*M, *q2 = W + 4*M, *v2 = W + 5*M;
    _Float16* wf = W + 6*M;
    float*    bs = (float*)(W + 6*M + 18432);
    _Float16* wo = W + 6*M + 18432 + 384;

    k_prep<<<1, 256, 0, stream>>>(w_in, b_in, gma, bta, mu, var, w_out, wf, bs, wo);
    k_conv_in<<<4096, 256, 0, stream>>>(x, wf, bs, q0, v0, q1, v1, q2, v2);
    k_attn_all<<<6144, 256, 0, stream>>>(q0, v0, q1, v1, q2, v2);
    k_conv_out<<<2048, 256, 0, stream>>>(v2, v0, v1, wo, b_out, out);
}